// Round 6
// baseline (138.112 us; speedup 1.0000x reference)
//
#include <hip/hip_runtime.h>

#define BB 8
#define TT 256
#define DD 512
#define AA 512

#define PS 2.8853900817779268f   // 2*log2(e)
#define LOG2E 1.4426950408889634f

typedef __attribute__((ext_vector_type(8))) short short8;
typedef __attribute__((ext_vector_type(4))) float f32x4;

__device__ __forceinline__ float fast_tanh(float x) {
    float e = __builtin_amdgcn_exp2f(x * PS);
    float r = __builtin_amdgcn_rcpf(1.0f + e);
    return fmaf(-2.0f, r, 1.0f);
}

__device__ __forceinline__ ushort f2bf(float x) {
    uint u = __float_as_uint(x);
    uint r = (u + 0x7fffu + ((u >> 16) & 1u)) >> 16;  // RNE
    return (ushort)r;
}
__device__ __forceinline__ float bf2f(ushort h) {
    return __uint_as_float(((uint)h) << 16);
}

// ---------------- prep: k0 (blocks 0..15) + conv_W (16..783) + conv_A (784..1807) --------
__global__ __launch_bounds__(256) void prep(const float* __restrict__ SO,
                                            ushort* __restrict__ Ast,
                                            const float* __restrict__ Wsh,
                                            const float* __restrict__ Wsi,
                                            const float* __restrict__ Wih,
                                            ushort* __restrict__ Wt,
                                            const float* __restrict__ fs_g,
                                            const float* __restrict__ Wii,
                                            const float* __restrict__ bii,
                                            float* __restrict__ ii) {
    const int bid = blockIdx.x;
    const int tid = threadIdx.x;
    __shared__ float T[32][33];
    __shared__ float fs[DD];

    if (bid < 16) {
        int b = bid >> 1, half = bid & 1;
        int a = half * 256 + tid;
        fs[tid]       = fs_g[b * DD + tid];
        fs[tid + 256] = fs_g[b * DD + tid + 256];
        __syncthreads();
        float acc = bii[a];
        #pragma unroll 8
        for (int d = 0; d < DD; ++d)
            acc = fmaf(fs[d], Wii[(size_t)d * AA + a], acc);
        ii[b * AA + a] = acc;
    } else if (bid < 784) {
        int lbid = bid - 16;
        int z = lbid >> 8;
        int rem = lbid & 255;
        const float* W = (z == 0) ? Wsh : (z == 1) ? Wsi : Wih;
        int k0 = (rem & 15) * 32, n0 = (rem >> 4) * 32;
        int tx = tid & 31, ty = tid >> 5;
        #pragma unroll
        for (int r = 0; r < 4; ++r) {
            int kl = ty * 4 + r;
            T[kl][tx] = W[(size_t)(k0 + kl) * 512 + n0 + tx];
        }
        __syncthreads();
        size_t nbase = (size_t)z * 512 + n0;
        #pragma unroll
        for (int r = 0; r < 4; ++r) {
            int nl = ty * 4 + r;
            float v = T[tx][nl];
            ushort hi = f2bf(v);
            ushort lo = f2bf(v - bf2f(hi));
            Wt[(nbase + nl) * 1024 + k0 + tx]       = hi;
            Wt[(nbase + nl) * 1024 + 512 + k0 + tx] = lo;
        }
    } else {
        int qid = (bid - 784) * 256 + tid;
        int m = qid >> 7;
        int k4 = (qid & 127) * 4;
        float4 v = *reinterpret_cast<const float4*>(&SO[(size_t)m * 512 + k4]);
        ushort4 hi, lo;
        hi.x = f2bf(v.x); lo.x = f2bf(v.x - bf2f(hi.x));
        hi.y = f2bf(v.y); lo.y = f2bf(v.y - bf2f(hi.y));
        hi.z = f2bf(v.z); lo.z = f2bf(v.z - bf2f(hi.z));
        hi.w = f2bf(v.w); lo.w = f2bf(v.w - bf2f(hi.w));
        *reinterpret_cast<ushort4*>(&Ast[(size_t)m * 1024 + k4])       = hi;
        *reinterpret_cast<ushort4*>(&Ast[(size_t)m * 1024 + 512 + k4]) = lo;
    }
}

// ---------------- gemm_mfma: 128x128 tile, direct-global frags, NO LDS, no barriers ------
// Logical K=1536: [0,512) A-hi x W-hi ; [512,1024) A-lo x W-hi ; [1024,1536) A-hi x W-lo
// by regions (BN=128): by 0-3 = sh -> EhT ; by 4-7 = si -> Es ; by 8-11 = ih -> ipart[8][]
#define GLOADK(AF, BF, K0) do {                                                        \
    const int ab_ = ((K0) < 1024 ? (K0) : (K0) - 1024) * 2;                            \
    const int bb_ = ((K0) < 512 ? (K0) : (K0) - 512) * 2;                              \
    _Pragma("unroll")                                                                  \
    for (int i_ = 0; i_ < 4; ++i_)                                                     \
        AF[i_] = *reinterpret_cast<const short8*>(Aptr + i_ * 32768 + ab_);            \
    _Pragma("unroll")                                                                  \
    for (int j_ = 0; j_ < 4; ++j_)                                                     \
        BF[j_] = *reinterpret_cast<const short8*>(Bptr + j_ * 32768 + bb_);            \
} while (0)

#define DOMFMA(AF, BF) do {                                                            \
    _Pragma("unroll")                                                                  \
    for (int i_ = 0; i_ < 4; ++i_)                                                     \
        _Pragma("unroll")                                                              \
        for (int j_ = 0; j_ < 4; ++j_)                                                 \
            acc[i_][j_] = __builtin_amdgcn_mfma_f32_16x16x32_bf16(                     \
                AF[i_], BF[j_], acc[i_][j_], 0, 0, 0);                                 \
} while (0)

__global__ __launch_bounds__(256) void gemm_mfma(
    const ushort* __restrict__ Ast, const ushort* __restrict__ Wt,
    const float* __restrict__ bsh, const float* __restrict__ bsi,
    const float* __restrict__ bih,
    const float* __restrict__ ii, const float* __restrict__ iv,
    float* __restrict__ EhT, float* __restrict__ Es, float* __restrict__ ipart) {
    const int tid = threadIdx.x;
    const int wave = tid >> 6, lane = tid & 63;
    const int wr = wave >> 1, wc = wave & 1;
    const int m0 = blockIdx.x * 128;
    const int by = blockIdx.y;
    const int n0 = by * 128;
    const int l15 = lane & 15, kb = lane >> 4;

    f32x4 acc[4][4] = {};

    const char* Aptr = reinterpret_cast<const char*>(Ast)
                       + (size_t)(m0 + wr * 64 + l15) * 2048 + kb * 16;
    const char* Bptr = reinterpret_cast<const char*>(Wt)
                       + (size_t)(n0 + wc * 64 + l15) * 2048 + kb * 16;

    short8 fA0[4], fB0[4], fA1[4], fB1[4];
    GLOADK(fA0, fB0, 0);
    for (int it = 0; it < 24; ++it) {
        const int k = it * 64;
        GLOADK(fA1, fB1, k + 32);
        DOMFMA(fA0, fB0);
        if (it < 23) GLOADK(fA0, fB0, k + 64);
        DOMFMA(fA1, fB1);
    }

    const int b = m0 >> 8;
    const int region = by >> 2;
    if (region == 0) {
        #pragma unroll
        for (int i = 0; i < 4; ++i) {
            int t0 = (m0 & 255) + wr * 64 + i * 16 + kb * 4;
            #pragma unroll
            for (int j = 0; j < 4; ++j) {
                int n = by * 128 + wc * 64 + j * 16 + l15;
                float bbv = bsh[n];
                float4 v;
                v.x = __builtin_amdgcn_exp2f((acc[i][j][0] + bbv) * PS);
                v.y = __builtin_amdgcn_exp2f((acc[i][j][1] + bbv) * PS);
                v.z = __builtin_amdgcn_exp2f((acc[i][j][2] + bbv) * PS);
                v.w = __builtin_amdgcn_exp2f((acc[i][j][3] + bbv) * PS);
                *reinterpret_cast<float4*>(&EhT[((size_t)b * 512 + n) * 256 + t0]) = v;
            }
        }
    } else if (region == 1) {
        #pragma unroll
        for (int i = 0; i < 4; ++i) {
            #pragma unroll
            for (int j = 0; j < 4; ++j) {
                int n = (by - 4) * 128 + wc * 64 + j * 16 + l15;
                float bbv = bsi[n];
                #pragma unroll
                for (int r = 0; r < 4; ++r) {
                    int m = m0 + wr * 64 + i * 16 + kb * 4 + r;
                    Es[(size_t)m * 512 + n] = __builtin_amdgcn_exp2f((acc[i][j][r] + bbv) * PS);
                }
            }
        }
    } else {
        int slot = (by - 8) * 2 + wc;
        #pragma unroll
        for (int i = 0; i < 4; ++i) {
            float p0 = 0.f, p1 = 0.f, p2 = 0.f, p3 = 0.f;
            #pragma unroll
            for (int j = 0; j < 4; ++j) {
                int n = (by - 8) * 128 + wc * 64 + j * 16 + l15;
                float add = bih[n] + ii[b * 512 + n];
                float w = iv[n];
                p0 = fmaf(w, fast_tanh(acc[i][j][0] + add), p0);
                p1 = fmaf(w, fast_tanh(acc[i][j][1] + add), p1);
                p2 = fmaf(w, fast_tanh(acc[i][j][2] + add), p2);
                p3 = fmaf(w, fast_tanh(acc[i][j][3] + add), p3);
            }
            #pragma unroll
            for (int off = 1; off < 16; off <<= 1) {
                p0 += __shfl_xor(p0, off);
                p1 += __shfl_xor(p1, off);
                p2 += __shfl_xor(p2, off);
                p3 += __shfl_xor(p3, off);
            }
            int mb = m0 + wr * 64 + i * 16 + kb * 4;
            if (l15 == 0) ipart[slot * 2048 + mb + 0] = p0;
            if (l15 == 1) ipart[slot * 2048 + mb + 1] = p1;
            if (l15 == 2) ipart[slot * 2048 + mb + 2] = p2;
            if (l15 == 3) ipart[slot * 2048 + mb + 3] = p3;
        }
    }
}

// ---------------- fallback fp32 GEMM path ----------------
#define TS 64
#define KS 16
#define LPAD 72

__global__ __launch_bounds__(256) void k0_ii(const float* __restrict__ fs_g,
                                             const float* __restrict__ Wii,
                                             const float* __restrict__ bii,
                                             float* __restrict__ ii) {
    int b = blockIdx.x, tid = threadIdx.x;
    int a = blockIdx.y * 256 + tid;
    __shared__ float fs[DD];
    fs[tid]       = fs_g[b * DD + tid];
    fs[tid + 256] = fs_g[b * DD + tid + 256];
    __syncthreads();
    float acc = bii[a];
    #pragma unroll 8
    for (int d = 0; d < DD; ++d)
        acc = fmaf(fs[d], Wii[(size_t)d * AA + a], acc);
    ii[b * AA + a] = acc;
}

__global__ __launch_bounds__(256) void k1_gemm_old(
    const float* __restrict__ SO,
    const float* __restrict__ Wsh, const float* __restrict__ bsh,
    const float* __restrict__ Wsi, const float* __restrict__ bsi,
    const float* __restrict__ Wih, const float* __restrict__ bih,
    const float* __restrict__ ii, const float* __restrict__ iv,
    float* __restrict__ EhT, float* __restrict__ Es, float* __restrict__ ipart) {
    const int mode = blockIdx.z;
    const float* W;
    const float* bias;
    if (mode == 0)      { W = Wsh; bias = bsh; }
    else if (mode == 1) { W = Wsi; bias = bsi; }
    else                { W = Wih; bias = bih; }

    const int m0 = blockIdx.x * TS;
    const int n0 = blockIdx.y * TS;
    const int tid = threadIdx.x;
    const int tx = tid & 15, ty = tid >> 4;

    __shared__ __align__(16) float As[KS][LPAD];
    __shared__ __align__(16) float Bs[KS][LPAD];
    __shared__ __align__(16) float Cs[TS][LPAD];

    float acc[4][4] = {};
    const int arow = tid >> 2;
    const int akc  = (tid & 3) * 4;
    const int brw  = tid >> 4;
    const int bnc  = (tid & 15) * 4;

    for (int k0 = 0; k0 < DD; k0 += KS) {
        float4 av = *reinterpret_cast<const float4*>(&SO[(m0 + arow) * DD + k0 + akc]);
        As[akc + 0][arow] = av.x;
        As[akc + 1][arow] = av.y;
        As[akc + 2][arow] = av.z;
        As[akc + 3][arow] = av.w;
        float4 bv = *reinterpret_cast<const float4*>(&W[(k0 + brw) * AA + n0 + bnc]);
        *reinterpret_cast<float4*>(&Bs[brw][bnc]) = bv;
        __syncthreads();
        #pragma unroll
        for (int kk = 0; kk < KS; ++kk) {
            float4 a4 = *reinterpret_cast<const float4*>(&As[kk][ty * 4]);
            float4 b4 = *reinterpret_cast<const float4*>(&Bs[kk][tx * 4]);
            float av_[4] = {a4.x, a4.y, a4.z, a4.w};
            float bv_[4] = {b4.x, b4.y, b4.z, b4.w};
            #pragma unroll
            for (int i = 0; i < 4; ++i)
                #pragma unroll
                for (int j = 0; j < 4; ++j)
                    acc[i][j] = fmaf(av_[i], bv_[j], acc[i][j]);
        }
        __syncthreads();
    }

    if (mode == 1) {
        #pragma unroll
        for (int i = 0; i < 4; ++i) {
            int m = m0 + ty * 4 + i;
            float4 v;
            v.x = __builtin_amdgcn_exp2f((acc[i][0] + bias[n0 + tx * 4 + 0]) * PS);
            v.y = __builtin_amdgcn_exp2f((acc[i][1] + bias[n0 + tx * 4 + 1]) * PS);
            v.z = __builtin_amdgcn_exp2f((acc[i][2] + bias[n0 + tx * 4 + 2]) * PS);
            v.w = __builtin_amdgcn_exp2f((acc[i][3] + bias[n0 + tx * 4 + 3]) * PS);
            *reinterpret_cast<float4*>(&Es[(size_t)m * AA + n0 + tx * 4]) = v;
        }
    } else if (mode == 0) {
        #pragma unroll
        for (int i = 0; i < 4; ++i)
            #pragma unroll
            for (int j = 0; j < 4; ++j)
                Cs[tx * 4 + j][ty * 4 + i] =
                    __builtin_amdgcn_exp2f((acc[i][j] + bias[n0 + tx * 4 + j]) * PS);
        __syncthreads();
        int row = tid >> 2, part = tid & 3;
        int bb = m0 >> 8;
        int tstart = (m0 & 255) + part * 16;
        float* dst = &EhT[bb * (AA * TT) + (n0 + row) * TT + tstart];
        #pragma unroll
        for (int q = 0; q < 4; ++q) {
            float4 v = *reinterpret_cast<const float4*>(&Cs[row][part * 16 + q * 4]);
            *reinterpret_cast<float4*>(&dst[q * 4]) = v;
        }
    } else {
        int bb = m0 >> 8;
        #pragma unroll
        for (int i = 0; i < 4; ++i) {
            float p = 0.f;
            #pragma unroll
            for (int j = 0; j < 4; ++j) {
                int n = n0 + tx * 4 + j;
                float x = acc[i][j] + bias[n] + ii[bb * AA + n];
                p = fmaf(iv[n], fast_tanh(x), p);
            }
            Cs[ty * 4 + i][tx] = p;
        }
        __syncthreads();
        if (tid < 64) {
            float s = 0.f;
            #pragma unroll
            for (int k = 0; k < 16; ++k) s += Cs[tid][k];
            ipart[blockIdx.y * 2048 + m0 + tid] = s;
        }
    }
}

// ---------------- k3_fused: 256 blocks x 512 thr, TGROUP=8; intent folded into tg==0 ----
// sigma = rcp(1 + Eh*Es); weight over s = exp2(PS*(ymin - y)) / sum, y = sum_a v*sigma.
// th = tid>>8 splits the a-range (each thread: 8 t-rows x 256 a = 8 indep rcp chains).
// Es/sv fetched via wave-uniform scalar loads; VGPR cap 256 for ILP (not occupancy).
__global__ __launch_bounds__(512, 2) void k3_fused(const float* __restrict__ SO,
                                                   const float* __restrict__ EhT,
                                                   const float* __restrict__ Es,
                                                   const float* __restrict__ sv_g,
                                                   const float* __restrict__ ipart,
                                                   float* __restrict__ out_cslot,
                                                   float* __restrict__ out_cint) {
    const int bid = blockIdx.x;          // 0..255
    const int tid = threadIdx.x;         // 0..511
    const int b  = bid & 7;              // XCD-affine
    const int tg = bid >> 3;             // 0..31
    const int t0 = tg * 8;
    const int s  = tid & 255;
    const int th = __builtin_amdgcn_readfirstlane(tid >> 8);  // 0/1, wave-uniform
    const int wq = (tid >> 6) & 3;

    __shared__ float yp[2][8][256];
    __shared__ __align__(16) float wlt[256][8];
    __shared__ float redm[2][8][4];
    __shared__ float reds[2][8][4];
    __shared__ float redI[256];
    __shared__ float wlI[256];

    // ---- score: 8 t-rows over this half's 256 a's ----
    {
        const float* er  = Es + (size_t)(b * 256 + t0) * 512 + th * 256;  // uniform
        const float* svp = sv_g + th * 256;                                // uniform
        const float* hp  = EhT + ((size_t)(b * 512 + th * 256)) * 256 + s;
        float y0=0.f,y1=0.f,y2=0.f,y3=0.f,y4=0.f,y5=0.f,y6=0.f,y7=0.f;
        for (int a0 = 0; a0 < 256; a0 += 8) {
            float h[8];
            #pragma unroll
            for (int u = 0; u < 8; ++u) h[u] = hp[(a0 + u) * 256];
            #pragma unroll
            for (int u = 0; u < 8; ++u) {
                const int a = a0 + u;
                const float v  = svp[a];
                const float hv = h[u];
                y0 = fmaf(v, __builtin_amdgcn_rcpf(fmaf(hv, er[a        ], 1.f)), y0);
                y1 = fmaf(v, __builtin_amdgcn_rcpf(fmaf(hv, er[a +  512], 1.f)), y1);
                y2 = fmaf(v, __builtin_amdgcn_rcpf(fmaf(hv, er[a + 1024], 1.f)), y2);
                y3 = fmaf(v, __builtin_amdgcn_rcpf(fmaf(hv, er[a + 1536], 1.f)), y3);
                y4 = fmaf(v, __builtin_amdgcn_rcpf(fmaf(hv, er[a + 2048], 1.f)), y4);
                y5 = fmaf(v, __builtin_amdgcn_rcpf(fmaf(hv, er[a + 2560], 1.f)), y5);
                y6 = fmaf(v, __builtin_amdgcn_rcpf(fmaf(hv, er[a + 3072], 1.f)), y6);
                y7 = fmaf(v, __builtin_amdgcn_rcpf(fmaf(hv, er[a + 3584], 1.f)), y7);
            }
        }
        yp[th][0][s]=y0; yp[th][1][s]=y1; yp[th][2][s]=y2; yp[th][3][s]=y3;
        yp[th][4][s]=y4; yp[th][5][s]=y5; yp[th][6][s]=y6; yp[th][7][s]=y7;
    }
    __syncthreads();

    // ---- softmax: half th owns rows th*4 .. th*4+3 ----
    float ys[4];
    #pragma unroll
    for (int q = 0; q < 4; ++q) {
        const int r = th * 4 + q;
        ys[q] = yp[0][r][s] + yp[1][r][s];
        float mn = ys[q];
        #pragma unroll
        for (int off = 1; off < 64; off <<= 1)
            mn = fminf(mn, __shfl_xor(mn, off));
        if ((tid & 63) == 0) redm[th][q][wq] = mn;
    }
    __syncthreads();
    #pragma unroll
    for (int q = 0; q < 4; ++q) {
        float mn = fminf(fminf(redm[th][q][0], redm[th][q][1]),
                         fminf(redm[th][q][2], redm[th][q][3]));
        float e = __builtin_amdgcn_exp2f(PS * (mn - ys[q]));
        float sm = e;
        #pragma unroll
        for (int off = 1; off < 64; off <<= 1)
            sm += __shfl_xor(sm, off);
        if ((tid & 63) == 0) reds[th][q][wq] = sm;
        ys[q] = e;
    }
    __syncthreads();
    #pragma unroll
    for (int q = 0; q < 4; ++q) {
        float sm = (reds[th][q][0] + reds[th][q][1]) + (reds[th][q][2] + reds[th][q][3]);
        wlt[s][th * 4 + q] = ys[q] * __builtin_amdgcn_rcpf(sm);
    }
    __syncthreads();

    // ---- PV: thread owns one d column, 8 t-rows ----
    {
        const int d = tid;  // 0..511
        const float* sop = SO + (size_t)b * (256 * 512) + d;
        float c0=0.f,c1=0.f,c2=0.f,c3=0.f,c4=0.f,c5=0.f,c6=0.f,c7=0.f;
        for (int s2 = 0; s2 < 256; s2 += 4) {
            float so[4];
            #pragma unroll
            for (int u = 0; u < 4; ++u) so[u] = sop[(s2 + u) * 512];
            #pragma unroll
            for (int u = 0; u < 4; ++u) {
                float4 w0 = *reinterpret_cast<const float4*>(&wlt[s2 + u][0]);
                float4 w1 = *reinterpret_cast<const float4*>(&wlt[s2 + u][4]);
                c0 = fmaf(w0.x, so[u], c0);
                c1 = fmaf(w0.y, so[u], c1);
                c2 = fmaf(w0.z, so[u], c2);
                c3 = fmaf(w0.w, so[u], c3);
                c4 = fmaf(w1.x, so[u], c4);
                c5 = fmaf(w1.y, so[u], c5);
                c6 = fmaf(w1.z, so[u], c6);
                c7 = fmaf(w1.w, so[u], c7);
            }
        }
        float* op = &out_cslot[((size_t)(b * 256 + t0)) * 512 + d];
        op[0*512]=c0; op[1*512]=c1; op[2*512]=c2; op[3*512]=c3;
        op[4*512]=c4; op[5*512]=c5; op[6*512]=c6; op[7*512]=c7;
    }

    // ---- intent (only tg==0 blocks; block-uniform branch) ----
    if (tg == 0) {
        __syncthreads();
        float sc = 0.f;
        if (tid < 256) {
            #pragma unroll
            for (int nb = 0; nb < 8; ++nb) sc += ipart[nb * 2048 + b * 256 + tid];
            redI[tid] = sc;
        }
        __syncthreads();
        for (int off = 128; off > 0; off >>= 1) {
            if (tid < off) redI[tid] = fmaxf(redI[tid], redI[tid + off]);
            __syncthreads();
        }
        float mx = redI[0];
        __syncthreads();
        float e = 0.f;
        if (tid < 256) { e = __builtin_amdgcn_exp2f((sc - mx) * LOG2E); redI[tid] = e; }
        __syncthreads();
        for (int off = 128; off > 0; off >>= 1) {
            if (tid < off) redI[tid] += redI[tid + off];
            __syncthreads();
        }
        if (tid < 256) wlI[tid] = e * __builtin_amdgcn_rcpf(redI[0]);
        __syncthreads();
        const int d = tid;
        float c = 0.f;
        const float* sop = SO + (size_t)b * (256 * 512) + d;
        for (int s2 = 0; s2 < 256; s2 += 4) {
            float so[4];
            #pragma unroll
            for (int u = 0; u < 4; ++u) so[u] = sop[(s2 + u) * 512];
            #pragma unroll
            for (int u = 0; u < 4; ++u) c = fmaf(wlI[s2 + u], so[u], c);
        }
        out_cint[(size_t)b * 512 + d] = c;
    }
}

extern "C" void kernel_launch(void* const* d_in, const int* in_sizes, int n_in,
                              void* d_out, int out_size, void* d_ws, size_t ws_size,
                              hipStream_t stream) {
    const float* SO  = (const float*)d_in[0];
    const float* FS  = (const float*)d_in[1];
    const float* IV  = (const float*)d_in[2];
    const float* Wih = (const float*)d_in[3];
    const float* bih = (const float*)d_in[4];
    const float* Wii = (const float*)d_in[5];
    const float* bii = (const float*)d_in[6];
    const float* SV  = (const float*)d_in[7];
    const float* Wsh = (const float*)d_in[8];
    const float* bsh = (const float*)d_in[9];
    const float* Wsi = (const float*)d_in[10];
    const float* bsi = (const float*)d_in[11];

    float* ws    = (float*)d_ws;
    float* EhT   = ws;                 // [8][512][256]  exp2'd   1,048,576 f
    float* Es    = ws + 1048576;       // [2048][512]    exp2'd   1,048,576 f
    float* ii    = ws + 2097152;       // [8][512]                4,096 f
    float* ipart = ws + 2101248;       // [16][2048]              32,768 f (8 used)
    ushort* Ast  = (ushort*)(ws + 2134016);  // [2048][1024] bf16
    ushort* Wt   = (ushort*)(ws + 3182592);  // [1536][1024] bf16
    const size_t NEED = (size_t)3969024 * 4;

    float* out_cslot = (float*)d_out;
    float* out_cint  = out_cslot + BB * TT * DD;

    if (ws_size >= NEED) {
        prep<<<1808, 256, 0, stream>>>(SO, Ast, Wsh, Wsi, Wih, Wt, FS, Wii, bii, ii);
        gemm_mfma<<<dim3(16, 12), 256, 0, stream>>>(Ast, Wt, bsh, bsi, bih, ii, IV,
                                                    EhT, Es, ipart);
        k3_fused<<<256, 512, 0, stream>>>(SO, EhT, Es, SV, ipart, out_cslot, out_cint);
    } else {
        k0_ii<<<dim3(BB, 2), 256, 0, stream>>>(FS, Wii, bii, ii);
        k1_gemm_old<<<dim3(32, 8, 3), 256, 0, stream>>>(SO, Wsh, bsh, Wsi, bsi, Wih, bih,
                                                        ii, IV, EhT, Es, ipart);
        k3_fused<<<256, 512, 0, stream>>>(SO, EhT, Es, SV, ipart, out_cslot, out_cint);
    }
}

// Round 7
// 128.950 us; speedup vs baseline: 1.0710x; 1.0710x over previous
//
#include <hip/hip_runtime.h>

#define BB 8
#define TT 256
#define DD 512
#define AA 512

#define PS 2.8853900817779268f   // 2*log2(e)
#define LOG2E 1.4426950408889634f

typedef __attribute__((ext_vector_type(8))) short short8;
typedef __attribute__((ext_vector_type(4))) float f32x4;

__device__ __forceinline__ float fast_tanh(float x) {
    float e = __builtin_amdgcn_exp2f(x * PS);
    float r = __builtin_amdgcn_rcpf(1.0f + e);
    return fmaf(-2.0f, r, 1.0f);
}

__device__ __forceinline__ ushort f2bf(float x) {
    uint u = __float_as_uint(x);
    uint r = (u + 0x7fffu + ((u >> 16) & 1u)) >> 16;  // RNE
    return (ushort)r;
}
__device__ __forceinline__ float bf2f(ushort h) {
    return __uint_as_float(((uint)h) << 16);
}

// ---------------- prep: k0 (blocks 0..15) + conv_W (16..783) + conv_A (784..1807) --------
__global__ __launch_bounds__(256) void prep(const float* __restrict__ SO,
                                            ushort* __restrict__ Ast,
                                            const float* __restrict__ Wsh,
                                            const float* __restrict__ Wsi,
                                            const float* __restrict__ Wih,
                                            ushort* __restrict__ Wt,
                                            const float* __restrict__ fs_g,
                                            const float* __restrict__ Wii,
                                            const float* __restrict__ bii,
                                            float* __restrict__ ii) {
    const int bid = blockIdx.x;
    const int tid = threadIdx.x;
    __shared__ float T[32][33];
    __shared__ float fs[DD];

    if (bid < 16) {
        int b = bid >> 1, half = bid & 1;
        int a = half * 256 + tid;
        fs[tid]       = fs_g[b * DD + tid];
        fs[tid + 256] = fs_g[b * DD + tid + 256];
        __syncthreads();
        float acc = bii[a];
        #pragma unroll 8
        for (int d = 0; d < DD; ++d)
            acc = fmaf(fs[d], Wii[(size_t)d * AA + a], acc);
        ii[b * AA + a] = acc;
    } else if (bid < 784) {
        int lbid = bid - 16;
        int z = lbid >> 8;
        int rem = lbid & 255;
        const float* W = (z == 0) ? Wsh : (z == 1) ? Wsi : Wih;
        int k0 = (rem & 15) * 32, n0 = (rem >> 4) * 32;
        int tx = tid & 31, ty = tid >> 5;
        #pragma unroll
        for (int r = 0; r < 4; ++r) {
            int kl = ty * 4 + r;
            T[kl][tx] = W[(size_t)(k0 + kl) * 512 + n0 + tx];
        }
        __syncthreads();
        size_t nbase = (size_t)z * 512 + n0;
        #pragma unroll
        for (int r = 0; r < 4; ++r) {
            int nl = ty * 4 + r;
            float v = T[tx][nl];
            ushort hi = f2bf(v);
            ushort lo = f2bf(v - bf2f(hi));
            Wt[(nbase + nl) * 1024 + k0 + tx]       = hi;
            Wt[(nbase + nl) * 1024 + 512 + k0 + tx] = lo;
        }
    } else {
        int qid = (bid - 784) * 256 + tid;
        int m = qid >> 7;
        int k4 = (qid & 127) * 4;
        float4 v = *reinterpret_cast<const float4*>(&SO[(size_t)m * 512 + k4]);
        ushort4 hi, lo;
        hi.x = f2bf(v.x); lo.x = f2bf(v.x - bf2f(hi.x));
        hi.y = f2bf(v.y); lo.y = f2bf(v.y - bf2f(hi.y));
        hi.z = f2bf(v.z); lo.z = f2bf(v.z - bf2f(hi.z));
        hi.w = f2bf(v.w); lo.w = f2bf(v.w - bf2f(hi.w));
        *reinterpret_cast<ushort4*>(&Ast[(size_t)m * 1024 + k4])       = hi;
        *reinterpret_cast<ushort4*>(&Ast[(size_t)m * 1024 + 512 + k4]) = lo;
    }
}

// ---------------- gemm_mfma: 64x64 tile, NO LDS, direct-global frag loads ----------------
// Logical K=1536: [0,512) A-hi x W-hi ; [512,1024) A-lo x W-hi ; [1024,1536) A-hi x W-lo
// Frag: 16 rows (l15) x 32 k; lane kb in 0..3 reads 16B at kb*16 -> full 64B line per row.
// Grid (32, 24): by<8 sh -> EhT ; by 8-15 si -> Es ; by 16-23 ih -> ipart[16][]
__global__ __launch_bounds__(256) void gemm_mfma(
    const ushort* __restrict__ Ast, const ushort* __restrict__ Wt,
    const float* __restrict__ bsh, const float* __restrict__ bsi,
    const float* __restrict__ bih,
    const float* __restrict__ ii, const float* __restrict__ iv,
    float* __restrict__ EhT, float* __restrict__ Es, float* __restrict__ ipart) {
    const int tid = threadIdx.x;
    const int wave = tid >> 6, lane = tid & 63;
    const int wr = wave >> 1, wc = wave & 1;
    const int m0 = blockIdx.x * 64;
    const int by = blockIdx.y;
    const int n0 = by * 64;
    const int l15 = lane & 15, kb = lane >> 4;   // kb 0..3

    f32x4 acc[2][2] = {};

    const char* Arow0 = reinterpret_cast<const char*>(Ast)
                        + (size_t)(m0 + wr * 32 + l15) * 2048 + kb * 16;
    const char* Arow1 = Arow0 + 16 * 2048;
    const char* Brow0 = reinterpret_cast<const char*>(Wt)
                        + (size_t)(n0 + wc * 32 + l15) * 2048 + kb * 16;
    const char* Brow1 = Brow0 + 16 * 2048;

    #define GLOAD(AF, BF, S) do {                                                  \
        const int kl_ = (S) * 32;                                                  \
        const int ab_ = (kl_ < 1024 ? kl_ : kl_ - 1024) * 2;                       \
        const int bb_ = (kl_ < 512  ? kl_ : kl_ - 512 ) * 2;                       \
        AF[0] = *reinterpret_cast<const short8*>(Arow0 + ab_);                     \
        AF[1] = *reinterpret_cast<const short8*>(Arow1 + ab_);                     \
        BF[0] = *reinterpret_cast<const short8*>(Brow0 + bb_);                     \
        BF[1] = *reinterpret_cast<const short8*>(Brow1 + bb_);                     \
    } while (0)

    #define DOMFMA(AF, BF) do {                                                    \
        acc[0][0] = __builtin_amdgcn_mfma_f32_16x16x32_bf16(AF[0], BF[0], acc[0][0], 0, 0, 0); \
        acc[0][1] = __builtin_amdgcn_mfma_f32_16x16x32_bf16(AF[0], BF[1], acc[0][1], 0, 0, 0); \
        acc[1][0] = __builtin_amdgcn_mfma_f32_16x16x32_bf16(AF[1], BF[0], acc[1][0], 0, 0, 0); \
        acc[1][1] = __builtin_amdgcn_mfma_f32_16x16x32_bf16(AF[1], BF[1], acc[1][1], 0, 0, 0); \
    } while (0)

    short8 f0A[2], f0B[2], f1A[2], f1B[2], f2A[2], f2B[2];
    GLOAD(f0A, f0B, 0);
    GLOAD(f1A, f1B, 1);
    for (int it = 0; it < 16; ++it) {
        const int s = it * 3;
        GLOAD(f2A, f2B, s + 2);
        DOMFMA(f0A, f0B);
        if (s + 3 < 48) GLOAD(f0A, f0B, s + 3);
        DOMFMA(f1A, f1B);
        if (s + 4 < 48) GLOAD(f1A, f1B, s + 4);
        DOMFMA(f2A, f2B);
    }

    const int b = m0 >> 8;
    if (by < 8) {
        #pragma unroll
        for (int i = 0; i < 2; ++i) {
            int t0 = (m0 & 255) + wr * 32 + i * 16 + kb * 4;
            #pragma unroll
            for (int j = 0; j < 2; ++j) {
                int n = n0 + wc * 32 + j * 16 + l15;
                float bbv = bsh[n];
                float4 v;
                v.x = __builtin_amdgcn_exp2f((acc[i][j][0] + bbv) * PS);
                v.y = __builtin_amdgcn_exp2f((acc[i][j][1] + bbv) * PS);
                v.z = __builtin_amdgcn_exp2f((acc[i][j][2] + bbv) * PS);
                v.w = __builtin_amdgcn_exp2f((acc[i][j][3] + bbv) * PS);
                *reinterpret_cast<float4*>(&EhT[((size_t)b * 512 + n) * 256 + t0]) = v;
            }
        }
    } else if (by < 16) {
        #pragma unroll
        for (int i = 0; i < 2; ++i) {
            #pragma unroll
            for (int j = 0; j < 2; ++j) {
                int n = n0 - 512 + wc * 32 + j * 16 + l15;
                float bbv = bsi[n];
                #pragma unroll
                for (int r = 0; r < 4; ++r) {
                    int m = m0 + wr * 32 + i * 16 + kb * 4 + r;
                    Es[(size_t)m * 512 + n] = __builtin_amdgcn_exp2f((acc[i][j][r] + bbv) * PS);
                }
            }
        }
    } else {
        int slot = (by - 16) * 2 + wc;
        #pragma unroll
        for (int i = 0; i < 2; ++i) {
            float p0 = 0.f, p1 = 0.f, p2 = 0.f, p3 = 0.f;
            #pragma unroll
            for (int j = 0; j < 2; ++j) {
                int n = n0 - 1024 + wc * 32 + j * 16 + l15;
                float add = bih[n] + ii[b * 512 + n];
                float w = iv[n];
                p0 = fmaf(w, fast_tanh(acc[i][j][0] + add), p0);
                p1 = fmaf(w, fast_tanh(acc[i][j][1] + add), p1);
                p2 = fmaf(w, fast_tanh(acc[i][j][2] + add), p2);
                p3 = fmaf(w, fast_tanh(acc[i][j][3] + add), p3);
            }
            #pragma unroll
            for (int off = 1; off < 16; off <<= 1) {
                p0 += __shfl_xor(p0, off);
                p1 += __shfl_xor(p1, off);
                p2 += __shfl_xor(p2, off);
                p3 += __shfl_xor(p3, off);
            }
            int mb = m0 + wr * 32 + i * 16 + kb * 4;
            if (l15 == 0) ipart[slot * 2048 + mb + 0] = p0;
            if (l15 == 1) ipart[slot * 2048 + mb + 1] = p1;
            if (l15 == 2) ipart[slot * 2048 + mb + 2] = p2;
            if (l15 == 3) ipart[slot * 2048 + mb + 3] = p3;
        }
    }
}

// ---------------- fallback fp32 GEMM path ----------------
#define TS 64
#define KS 16
#define LPAD 72

__global__ __launch_bounds__(256) void k0_ii(const float* __restrict__ fs_g,
                                             const float* __restrict__ Wii,
                                             const float* __restrict__ bii,
                                             float* __restrict__ ii) {
    int b = blockIdx.x, tid = threadIdx.x;
    int a = blockIdx.y * 256 + tid;
    __shared__ float fs[DD];
    fs[tid]       = fs_g[b * DD + tid];
    fs[tid + 256] = fs_g[b * DD + tid + 256];
    __syncthreads();
    float acc = bii[a];
    #pragma unroll 8
    for (int d = 0; d < DD; ++d)
        acc = fmaf(fs[d], Wii[(size_t)d * AA + a], acc);
    ii[b * AA + a] = acc;
}

__global__ __launch_bounds__(256) void k1_gemm_old(
    const float* __restrict__ SO,
    const float* __restrict__ Wsh, const float* __restrict__ bsh,
    const float* __restrict__ Wsi, const float* __restrict__ bsi,
    const float* __restrict__ Wih, const float* __restrict__ bih,
    const float* __restrict__ ii, const float* __restrict__ iv,
    float* __restrict__ EhT, float* __restrict__ Es, float* __restrict__ ipart) {
    const int mode = blockIdx.z;
    const float* W;
    const float* bias;
    if (mode == 0)      { W = Wsh; bias = bsh; }
    else if (mode == 1) { W = Wsi; bias = bsi; }
    else                { W = Wih; bias = bih; }

    const int m0 = blockIdx.x * TS;
    const int n0 = blockIdx.y * TS;
    const int tid = threadIdx.x;
    const int tx = tid & 15, ty = tid >> 4;

    __shared__ __align__(16) float As[KS][LPAD];
    __shared__ __align__(16) float Bs[KS][LPAD];
    __shared__ __align__(16) float Cs[TS][LPAD];

    float acc[4][4] = {};
    const int arow = tid >> 2;
    const int akc  = (tid & 3) * 4;
    const int brw  = tid >> 4;
    const int bnc  = (tid & 15) * 4;

    for (int k0 = 0; k0 < DD; k0 += KS) {
        float4 av = *reinterpret_cast<const float4*>(&SO[(m0 + arow) * DD + k0 + akc]);
        As[akc + 0][arow] = av.x;
        As[akc + 1][arow] = av.y;
        As[akc + 2][arow] = av.z;
        As[akc + 3][arow] = av.w;
        float4 bv = *reinterpret_cast<const float4*>(&W[(k0 + brw) * AA + n0 + bnc]);
        *reinterpret_cast<float4*>(&Bs[brw][bnc]) = bv;
        __syncthreads();
        #pragma unroll
        for (int kk = 0; kk < KS; ++kk) {
            float4 a4 = *reinterpret_cast<const float4*>(&As[kk][ty * 4]);
            float4 b4 = *reinterpret_cast<const float4*>(&Bs[kk][tx * 4]);
            float av_[4] = {a4.x, a4.y, a4.z, a4.w};
            float bv_[4] = {b4.x, b4.y, b4.z, b4.w};
            #pragma unroll
            for (int i = 0; i < 4; ++i)
                #pragma unroll
                for (int j = 0; j < 4; ++j)
                    acc[i][j] = fmaf(av_[i], bv_[j], acc[i][j]);
        }
        __syncthreads();
    }

    if (mode == 1) {
        #pragma unroll
        for (int i = 0; i < 4; ++i) {
            int m = m0 + ty * 4 + i;
            float4 v;
            v.x = __builtin_amdgcn_exp2f((acc[i][0] + bias[n0 + tx * 4 + 0]) * PS);
            v.y = __builtin_amdgcn_exp2f((acc[i][1] + bias[n0 + tx * 4 + 1]) * PS);
            v.z = __builtin_amdgcn_exp2f((acc[i][2] + bias[n0 + tx * 4 + 2]) * PS);
            v.w = __builtin_amdgcn_exp2f((acc[i][3] + bias[n0 + tx * 4 + 3]) * PS);
            *reinterpret_cast<float4*>(&Es[(size_t)m * AA + n0 + tx * 4]) = v;
        }
    } else if (mode == 0) {
        #pragma unroll
        for (int i = 0; i < 4; ++i)
            #pragma unroll
            for (int j = 0; j < 4; ++j)
                Cs[tx * 4 + j][ty * 4 + i] =
                    __builtin_amdgcn_exp2f((acc[i][j] + bias[n0 + tx * 4 + j]) * PS);
        __syncthreads();
        int row = tid >> 2, part = tid & 3;
        int bb = m0 >> 8;
        int tstart = (m0 & 255) + part * 16;
        float* dst = &EhT[bb * (AA * TT) + (n0 + row) * TT + tstart];
        #pragma unroll
        for (int q = 0; q < 4; ++q) {
            float4 v = *reinterpret_cast<const float4*>(&Cs[row][part * 16 + q * 4]);
            *reinterpret_cast<float4*>(&dst[q * 4]) = v;
        }
    } else {
        int bb = m0 >> 8;
        #pragma unroll
        for (int i = 0; i < 4; ++i) {
            float p = 0.f;
            #pragma unroll
            for (int j = 0; j < 4; ++j) {
                int n = n0 + tx * 4 + j;
                float x = acc[i][j] + bias[n] + ii[bb * AA + n];
                p = fmaf(iv[n], fast_tanh(x), p);
            }
            Cs[ty * 4 + i][tx] = p;
        }
        __syncthreads();
        if (tid < 64) {
            float s = 0.f;
            #pragma unroll
            for (int k = 0; k < 16; ++k) s += Cs[tid][k];
            ipart[blockIdx.y * 2048 + m0 + tid] = s;
        }
    }
}

// ---------------- k3_fused: intent (blocks 0..7) + slot score/softmax/PV (8..519) -------
// sigma = rcp(1 + Eh*Es); weight over s = exp2(PS*(ymin - y)) / sum, y = sum_a v*sigma
__global__ __launch_bounds__(512) void k3_fused(const float* __restrict__ SO,
                                                const float* __restrict__ EhT,
                                                const float* __restrict__ Es,
                                                const float* __restrict__ sv_g,
                                                const float* __restrict__ ipart,
                                                float* __restrict__ out_cslot,
                                                float* __restrict__ out_cint,
                                                int npart) {
    const int bid = blockIdx.x;
    const int tid = threadIdx.x;

    __shared__ __align__(16) float est[512][4];
    __shared__ float sv[512];
    __shared__ float yp[2][4][256];
    __shared__ __align__(16) float wlt[256][4];
    __shared__ float redm[4][4];
    __shared__ float reds[4][4];
    __shared__ float redI[256];
    __shared__ float wlI[256];

    if (bid >= 8) {
        const int sb_ = bid - 8;
        const int b = sb_ & 7;          // XCD-affine
        const int t0 = (sb_ >> 3) * 4;
        const int s = tid & 255, ah = tid >> 8;

        // stage Es rows (4 t's, transposed) + sv
        {
            const float* esrc = &Es[(size_t)(b * 256 + t0) * 512];
            #pragma unroll
            for (int i = tid; i < 2048; i += 512) est[i & 511][i >> 9] = esrc[i];
            sv[tid] = sv_g[tid];
        }
        __syncthreads();

        const int abase = ah * 256;
        const float* hp = &EhT[((size_t)b * 512 + abase) * 256 + s];
        float y0 = 0.f, y1 = 0.f, y2 = 0.f, y3 = 0.f;
        for (int a0 = 0; a0 < 256; a0 += 8) {
            float h[8];
            #pragma unroll
            for (int u = 0; u < 8; ++u) h[u] = hp[(a0 + u) * 256];
            #pragma unroll
            for (int u = 0; u < 8; ++u) {
                int a = abase + a0 + u;
                float4 e4 = *reinterpret_cast<const float4*>(&est[a][0]);
                float v = sv[a];
                float x0 = fmaf(h[u], e4.x, 1.0f);
                y0 = fmaf(v, __builtin_amdgcn_rcpf(x0), y0);
                float x1 = fmaf(h[u], e4.y, 1.0f);
                y1 = fmaf(v, __builtin_amdgcn_rcpf(x1), y1);
                float x2 = fmaf(h[u], e4.z, 1.0f);
                y2 = fmaf(v, __builtin_amdgcn_rcpf(x2), y2);
                float x3 = fmaf(h[u], e4.w, 1.0f);
                y3 = fmaf(v, __builtin_amdgcn_rcpf(x3), y3);
            }
        }
        yp[ah][0][s] = y0; yp[ah][1][s] = y1; yp[ah][2][s] = y2; yp[ah][3][s] = y3;
        __syncthreads();

        const int wg = (tid >> 6) & 3;
        #pragma unroll
        for (int r = 0; r < 2; ++r) {
            int q = ah * 2 + r;
            float y = yp[0][q][s] + yp[1][q][s];
            float mn = y;
            #pragma unroll
            for (int off = 1; off < 64; off <<= 1)
                mn = fminf(mn, __shfl_xor(mn, off));
            if ((tid & 63) == 0) redm[q][wg] = mn;
            __syncthreads();
            mn = fminf(fminf(redm[q][0], redm[q][1]), fminf(redm[q][2], redm[q][3]));
            float e = __builtin_amdgcn_exp2f(PS * (mn - y));
            float sm = e;
            #pragma unroll
            for (int off = 1; off < 64; off <<= 1)
                sm += __shfl_xor(sm, off);
            if ((tid & 63) == 0) reds[q][wg] = sm;
            __syncthreads();
            sm = (reds[q][0] + reds[q][1]) + (reds[q][2] + reds[q][3]);
            wlt[s][q] = e * __builtin_amdgcn_rcpf(sm);
        }
        __syncthreads();

        // PV: thread owns d = tid
        const int d = tid;
        const float* sop = &SO[(size_t)b * 256 * 512 + d];
        float c0 = 0.f, c1 = 0.f, c2 = 0.f, c3 = 0.f;
        for (int s0 = 0; s0 < 256; s0 += 4) {
            float so[4];
            #pragma unroll
            for (int u = 0; u < 4; ++u) so[u] = sop[(s0 + u) * 512];
            #pragma unroll
            for (int u = 0; u < 4; ++u) {
                float4 w4 = *reinterpret_cast<const float4*>(&wlt[s0 + u][0]);
                c0 = fmaf(w4.x, so[u], c0);
                c1 = fmaf(w4.y, so[u], c1);
                c2 = fmaf(w4.z, so[u], c2);
                c3 = fmaf(w4.w, so[u], c3);
            }
        }
        float* op = &out_cslot[((size_t)(b * 256 + t0)) * 512 + d];
        op[0] = c0; op[512] = c1; op[1024] = c2; op[1536] = c3;
    } else {
        // ---- intent path (blocks 0..7, dispatched first -> no tail) ----
        const int b = bid;
        float sc = 0.f;
        if (tid < 256) {
            for (int nb = 0; nb < npart; ++nb) sc += ipart[nb * 2048 + b * 256 + tid];
            redI[tid] = sc;
        }
        __syncthreads();
        for (int off = 128; off > 0; off >>= 1) {
            if (tid < off) redI[tid] = fmaxf(redI[tid], redI[tid + off]);
            __syncthreads();
        }
        float mx = redI[0];
        __syncthreads();
        float e = 0.f;
        if (tid < 256) { e = __builtin_amdgcn_exp2f((sc - mx) * LOG2E); redI[tid] = e; }
        __syncthreads();
        for (int off = 128; off > 0; off >>= 1) {
            if (tid < off) redI[tid] += redI[tid + off];
            __syncthreads();
        }
        if (tid < 256) wlI[tid] = e * __builtin_amdgcn_rcpf(redI[0]);
        __syncthreads();
        const int d = tid;
        float c = 0.f;
        const float* sop = &SO[(size_t)b * 256 * 512 + d];
        for (int s0 = 0; s0 < 256; s0 += 4) {
            float so[4];
            #pragma unroll
            for (int u = 0; u < 4; ++u) so[u] = sop[(s0 + u) * 512];
            #pragma unroll
            for (int u = 0; u < 4; ++u) c = fmaf(wlI[s0 + u], so[u], c);
        }
        out_cint[(size_t)b * 512 + d] = c;
    }
}

extern "C" void kernel_launch(void* const* d_in, const int* in_sizes, int n_in,
                              void* d_out, int out_size, void* d_ws, size_t ws_size,
                              hipStream_t stream) {
    const float* SO  = (const float*)d_in[0];
    const float* FS  = (const float*)d_in[1];
    const float* IV  = (const float*)d_in[2];
    const float* Wih = (const float*)d_in[3];
    const float* bih = (const float*)d_in[4];
    const float* Wii = (const float*)d_in[5];
    const float* bii = (const float*)d_in[6];
    const float* SV  = (const float*)d_in[7];
    const float* Wsh = (const float*)d_in[8];
    const float* bsh = (const float*)d_in[9];
    const float* Wsi = (const float*)d_in[10];
    const float* bsi = (const float*)d_in[11];

    float* ws    = (float*)d_ws;
    float* EhT   = ws;                 // [8][512][256]  exp2'd   1,048,576 f
    float* Es    = ws + 1048576;       // [2048][512]    exp2'd   1,048,576 f
    float* ii    = ws + 2097152;       // [8][512]                4,096 f
    float* ipart = ws + 2101248;       // [16][2048]              32,768 f
    ushort* Ast  = (ushort*)(ws + 2134016);  // [2048][1024] bf16
    ushort* Wt   = (ushort*)(ws + 3182592);  // [1536][1024] bf16
    const size_t NEED = (size_t)3969024 * 4;

    float* out_cslot = (float*)d_out;
    float* out_cint  = out_cslot + BB * TT * DD;

    if (ws_size >= NEED) {
        prep<<<1808, 256, 0, stream>>>(SO, Ast, Wsh, Wsi, Wih, Wt, FS, Wii, bii, ii);
        gemm_mfma<<<dim3(32, 24), 256, 0, stream>>>(Ast, Wt, bsh, bsi, bih, ii, IV,
                                                    EhT, Es, ipart);
        k3_fused<<<520, 512, 0, stream>>>(SO, EhT, Es, SV, ipart, out_cslot, out_cint, 16);
    } else {
        k0_ii<<<dim3(BB, 2), 256, 0, stream>>>(FS, Wii, bii, ii);
        k1_gemm_old<<<dim3(32, 8, 3), 256, 0, stream>>>(SO, Wsh, bsh, Wsi, bsi, Wih, bih,
                                                        ii, IV, EhT, Es, ipart);
        k3_fused<<<520, 512, 0, stream>>>(SO, EhT, Es, SV, ipart, out_cslot, out_cint, 8);
    }
}

// Round 8
// 113.324 us; speedup vs baseline: 1.2187x; 1.1379x over previous
//
#include <hip/hip_runtime.h>

#define BB 8
#define TT 256
#define DD 512
#define AA 512

#define PS 2.8853900817779268f   // 2*log2(e)
#define LOG2E 1.4426950408889634f

typedef __attribute__((ext_vector_type(8))) short short8;
typedef __attribute__((ext_vector_type(4))) float f32x4;

__device__ __forceinline__ float fast_tanh(float x) {
    float e = __builtin_amdgcn_exp2f(x * PS);
    float r = __builtin_amdgcn_rcpf(1.0f + e);
    return fmaf(-2.0f, r, 1.0f);
}

__device__ __forceinline__ ushort f2bf(float x) {
    uint u = __float_as_uint(x);
    uint r = (u + 0x7fffu + ((u >> 16) & 1u)) >> 16;  // RNE
    return (ushort)r;
}
__device__ __forceinline__ float bf2f(ushort h) {
    return __uint_as_float(((uint)h) << 16);
}

// ---------------- prep: k0 (blocks 0..15) + conv_W (16..783) + conv_A (784..1807) --------
__global__ __launch_bounds__(256) void prep(const float* __restrict__ SO,
                                            ushort* __restrict__ Ast,
                                            const float* __restrict__ Wsh,
                                            const float* __restrict__ Wsi,
                                            const float* __restrict__ Wih,
                                            ushort* __restrict__ Wt,
                                            const float* __restrict__ fs_g,
                                            const float* __restrict__ Wii,
                                            const float* __restrict__ bii,
                                            float* __restrict__ ii) {
    const int bid = blockIdx.x;
    const int tid = threadIdx.x;
    __shared__ float T[32][33];
    __shared__ float fs[DD];

    if (bid < 16) {
        int b = bid >> 1, half = bid & 1;
        int a = half * 256 + tid;
        fs[tid]       = fs_g[b * DD + tid];
        fs[tid + 256] = fs_g[b * DD + tid + 256];
        __syncthreads();
        float acc = bii[a];
        #pragma unroll 8
        for (int d = 0; d < DD; ++d)
            acc = fmaf(fs[d], Wii[(size_t)d * AA + a], acc);
        ii[b * AA + a] = acc;
    } else if (bid < 784) {
        int lbid = bid - 16;
        int z = lbid >> 8;
        int rem = lbid & 255;
        const float* W = (z == 0) ? Wsh : (z == 1) ? Wsi : Wih;
        int k0 = (rem & 15) * 32, n0 = (rem >> 4) * 32;
        int tx = tid & 31, ty = tid >> 5;
        #pragma unroll
        for (int r = 0; r < 4; ++r) {
            int kl = ty * 4 + r;
            T[kl][tx] = W[(size_t)(k0 + kl) * 512 + n0 + tx];
        }
        __syncthreads();
        size_t nbase = (size_t)z * 512 + n0;
        #pragma unroll
        for (int r = 0; r < 4; ++r) {
            int nl = ty * 4 + r;
            float v = T[tx][nl];
            ushort hi = f2bf(v);
            ushort lo = f2bf(v - bf2f(hi));
            Wt[(nbase + nl) * 1024 + k0 + tx]       = hi;
            Wt[(nbase + nl) * 1024 + 512 + k0 + tx] = lo;
        }
    } else {
        int qid = (bid - 784) * 256 + tid;
        int m = qid >> 7;
        int k4 = (qid & 127) * 4;
        float4 v = *reinterpret_cast<const float4*>(&SO[(size_t)m * 512 + k4]);
        ushort4 hi, lo;
        hi.x = f2bf(v.x); lo.x = f2bf(v.x - bf2f(hi.x));
        hi.y = f2bf(v.y); lo.y = f2bf(v.y - bf2f(hi.y));
        hi.z = f2bf(v.z); lo.z = f2bf(v.z - bf2f(hi.z));
        hi.w = f2bf(v.w); lo.w = f2bf(v.w - bf2f(hi.w));
        *reinterpret_cast<ushort4*>(&Ast[(size_t)m * 1024 + k4])       = hi;
        *reinterpret_cast<ushort4*>(&Ast[(size_t)m * 1024 + 512 + k4]) = lo;
    }
}

// ---------------- gemm_mfma: 128x128 tile, BK=32, LDS double-buffer (round-4 proven) -----
// Logical K=1536: [0,512) A-hi x W-hi ; [512,1024) A-lo x W-hi ; [1024,1536) A-hi x W-lo
// by regions (BN=128): by 0-3 = sh -> EhT ; by 4-7 = si -> Es ; by 8-11 = ih -> ipart[8][]
__global__ __launch_bounds__(256) void gemm_mfma(
    const ushort* __restrict__ Ast, const ushort* __restrict__ Wt,
    const float* __restrict__ bsh, const float* __restrict__ bsi,
    const float* __restrict__ bih,
    const float* __restrict__ ii, const float* __restrict__ iv,
    float* __restrict__ EhT, float* __restrict__ Es, float* __restrict__ ipart) {
    __shared__ __align__(16) ushort Al[2][128 * 32];
    __shared__ __align__(16) ushort Bl[2][128 * 32];
    const int tid = threadIdx.x;
    const int wave = tid >> 6, lane = tid & 63;
    const int wr = wave >> 1, wc = wave & 1;
    const int m0 = blockIdx.x * 128;
    const int by = blockIdx.y;
    const int l15 = lane & 15, kb = lane >> 4;

    f32x4 acc[4][4] = {};

    const char* Ab = reinterpret_cast<const char*>(Ast);
    const char* Bb = reinterpret_cast<const char*>(Wt);
    char* AlB = reinterpret_cast<char*>(&Al[0][0]);
    char* BlB = reinterpret_cast<char*>(&Bl[0][0]);

    // staging geometry: thread covers row=tid>>1, two 16B slots starting at (tid&1)*2
    const int srow  = tid >> 1;
    const int sslot = (tid & 1) * 2;
    const int swz   = (srow >> 1) & 3;
    const int lw0 = srow * 64 + ((sslot    ) ^ swz) * 16;
    const int lw1 = srow * 64 + ((sslot + 1) ^ swz) * 16;
    const char* agp = Ab + (size_t)(m0 + srow) * 2048 + sslot * 16;
    const char* bgp = Bb + (size_t)(by * 128 + srow) * 2048 + sslot * 16;

    // frag read offsets (within one 8KB buffer)
    int aro[4], bro[4];
    #pragma unroll
    for (int i = 0; i < 4; ++i) {
        int ra = wr * 64 + i * 16 + l15;
        aro[i] = ra * 64 + ((kb ^ ((ra >> 1) & 3)) * 16);
        int rb = wc * 64 + i * 16 + l15;
        bro[i] = rb * 64 + ((kb ^ ((rb >> 1) & 3)) * 16);
    }

    #define ABYTE(k0) (((k0) < 1024 ? (k0) : (k0) - 1024) * 2)
    #define BBYTE(k0) (((k0) < 512 ? (k0) : (k0) - 512) * 2)

    // prologue: stage k0=0 into buf0
    {
        short8 a0 = *reinterpret_cast<const short8*>(agp + ABYTE(0));
        short8 a1 = *reinterpret_cast<const short8*>(agp + ABYTE(0) + 16);
        short8 b0 = *reinterpret_cast<const short8*>(bgp + BBYTE(0));
        short8 b1 = *reinterpret_cast<const short8*>(bgp + BBYTE(0) + 16);
        *reinterpret_cast<short8*>(AlB + lw0) = a0;
        *reinterpret_cast<short8*>(AlB + lw1) = a1;
        *reinterpret_cast<short8*>(BlB + lw0) = b0;
        *reinterpret_cast<short8*>(BlB + lw1) = b1;
    }
    __syncthreads();

    int cur = 0;
    for (int it = 0; it < 48; ++it) {
        short8 a0, a1, b0, b1;
        const bool pf = (it + 1 < 48);
        if (pf) {
            int k0 = (it + 1) * 32;
            int ab = ABYTE(k0), bb = BBYTE(k0);
            a0 = *reinterpret_cast<const short8*>(agp + ab);
            a1 = *reinterpret_cast<const short8*>(agp + ab + 16);
            b0 = *reinterpret_cast<const short8*>(bgp + bb);
            b1 = *reinterpret_cast<const short8*>(bgp + bb + 16);
        }
        const char* Ac = AlB + cur * 8192;
        const char* Bc = BlB + cur * 8192;
        short8 af[4], bf[4];
        #pragma unroll
        for (int i = 0; i < 4; ++i) {
            af[i] = *reinterpret_cast<const short8*>(Ac + aro[i]);
            bf[i] = *reinterpret_cast<const short8*>(Bc + bro[i]);
        }
        #pragma unroll
        for (int i = 0; i < 4; ++i)
            #pragma unroll
            for (int j = 0; j < 4; ++j)
                acc[i][j] = __builtin_amdgcn_mfma_f32_16x16x32_bf16(
                    af[i], bf[j], acc[i][j], 0, 0, 0);
        if (pf) {
            char* An = AlB + (cur ^ 1) * 8192;
            char* Bn = BlB + (cur ^ 1) * 8192;
            *reinterpret_cast<short8*>(An + lw0) = a0;
            *reinterpret_cast<short8*>(An + lw1) = a1;
            *reinterpret_cast<short8*>(Bn + lw0) = b0;
            *reinterpret_cast<short8*>(Bn + lw1) = b1;
        }
        __syncthreads();
        cur ^= 1;
    }

    const int b = m0 >> 8;
    const int region = by >> 2;
    if (region == 0) {
        // sh -> EhT[b][n][t] = exp2(PS*(sh+bsh)); t along acc reg index
        #pragma unroll
        for (int i = 0; i < 4; ++i) {
            int t0 = (m0 & 255) + wr * 64 + i * 16 + kb * 4;
            #pragma unroll
            for (int j = 0; j < 4; ++j) {
                int n = by * 128 + wc * 64 + j * 16 + l15;
                float bbv = bsh[n];
                float4 v;
                v.x = __builtin_amdgcn_exp2f((acc[i][j][0] + bbv) * PS);
                v.y = __builtin_amdgcn_exp2f((acc[i][j][1] + bbv) * PS);
                v.z = __builtin_amdgcn_exp2f((acc[i][j][2] + bbv) * PS);
                v.w = __builtin_amdgcn_exp2f((acc[i][j][3] + bbv) * PS);
                *reinterpret_cast<float4*>(&EhT[((size_t)b * 512 + n) * 256 + t0]) = v;
            }
        }
    } else if (region == 1) {
        #pragma unroll
        for (int i = 0; i < 4; ++i) {
            #pragma unroll
            for (int j = 0; j < 4; ++j) {
                int n = (by - 4) * 128 + wc * 64 + j * 16 + l15;
                float bbv = bsi[n];
                #pragma unroll
                for (int r = 0; r < 4; ++r) {
                    int m = m0 + wr * 64 + i * 16 + kb * 4 + r;
                    Es[(size_t)m * 512 + n] = __builtin_amdgcn_exp2f((acc[i][j][r] + bbv) * PS);
                }
            }
        }
    } else {
        int slot = (by - 8) * 2 + wc;
        #pragma unroll
        for (int i = 0; i < 4; ++i) {
            float p0 = 0.f, p1 = 0.f, p2 = 0.f, p3 = 0.f;
            #pragma unroll
            for (int j = 0; j < 4; ++j) {
                int n = (by - 8) * 128 + wc * 64 + j * 16 + l15;
                float add = bih[n] + ii[b * 512 + n];
                float w = iv[n];
                p0 = fmaf(w, fast_tanh(acc[i][j][0] + add), p0);
                p1 = fmaf(w, fast_tanh(acc[i][j][1] + add), p1);
                p2 = fmaf(w, fast_tanh(acc[i][j][2] + add), p2);
                p3 = fmaf(w, fast_tanh(acc[i][j][3] + add), p3);
            }
            #pragma unroll
            for (int off = 1; off < 16; off <<= 1) {
                p0 += __shfl_xor(p0, off);
                p1 += __shfl_xor(p1, off);
                p2 += __shfl_xor(p2, off);
                p3 += __shfl_xor(p3, off);
            }
            int mb = m0 + wr * 64 + i * 16 + kb * 4;
            if (l15 == 0) ipart[slot * 2048 + mb + 0] = p0;
            if (l15 == 1) ipart[slot * 2048 + mb + 1] = p1;
            if (l15 == 2) ipart[slot * 2048 + mb + 2] = p2;
            if (l15 == 3) ipart[slot * 2048 + mb + 3] = p3;
        }
    }
}

// ---------------- fallback fp32 GEMM path ----------------
#define TS 64
#define KS 16
#define LPAD 72

__global__ __launch_bounds__(256) void k0_ii(const float* __restrict__ fs_g,
                                             const float* __restrict__ Wii,
                                             const float* __restrict__ bii,
                                             float* __restrict__ ii) {
    int b = blockIdx.x, tid = threadIdx.x;
    int a = blockIdx.y * 256 + tid;
    __shared__ float fs[DD];
    fs[tid]       = fs_g[b * DD + tid];
    fs[tid + 256] = fs_g[b * DD + tid + 256];
    __syncthreads();
    float acc = bii[a];
    #pragma unroll 8
    for (int d = 0; d < DD; ++d)
        acc = fmaf(fs[d], Wii[(size_t)d * AA + a], acc);
    ii[b * AA + a] = acc;
}

__global__ __launch_bounds__(256) void k1_gemm_old(
    const float* __restrict__ SO,
    const float* __restrict__ Wsh, const float* __restrict__ bsh,
    const float* __restrict__ Wsi, const float* __restrict__ bsi,
    const float* __restrict__ Wih, const float* __restrict__ bih,
    const float* __restrict__ ii, const float* __restrict__ iv,
    float* __restrict__ EhT, float* __restrict__ Es, float* __restrict__ ipart) {
    const int mode = blockIdx.z;
    const float* W;
    const float* bias;
    if (mode == 0)      { W = Wsh; bias = bsh; }
    else if (mode == 1) { W = Wsi; bias = bsi; }
    else                { W = Wih; bias = bih; }

    const int m0 = blockIdx.x * TS;
    const int n0 = blockIdx.y * TS;
    const int tid = threadIdx.x;
    const int tx = tid & 15, ty = tid >> 4;

    __shared__ __align__(16) float As[KS][LPAD];
    __shared__ __align__(16) float Bs[KS][LPAD];
    __shared__ __align__(16) float Cs[TS][LPAD];

    float acc[4][4] = {};
    const int arow = tid >> 2;
    const int akc  = (tid & 3) * 4;
    const int brw  = tid >> 4;
    const int bnc  = (tid & 15) * 4;

    for (int k0 = 0; k0 < DD; k0 += KS) {
        float4 av = *reinterpret_cast<const float4*>(&SO[(m0 + arow) * DD + k0 + akc]);
        As[akc + 0][arow] = av.x;
        As[akc + 1][arow] = av.y;
        As[akc + 2][arow] = av.z;
        As[akc + 3][arow] = av.w;
        float4 bv = *reinterpret_cast<const float4*>(&W[(k0 + brw) * AA + n0 + bnc]);
        *reinterpret_cast<float4*>(&Bs[brw][bnc]) = bv;
        __syncthreads();
        #pragma unroll
        for (int kk = 0; kk < KS; ++kk) {
            float4 a4 = *reinterpret_cast<const float4*>(&As[kk][ty * 4]);
            float4 b4 = *reinterpret_cast<const float4*>(&Bs[kk][tx * 4]);
            float av_[4] = {a4.x, a4.y, a4.z, a4.w};
            float bv_[4] = {b4.x, b4.y, b4.z, b4.w};
            #pragma unroll
            for (int i = 0; i < 4; ++i)
                #pragma unroll
                for (int j = 0; j < 4; ++j)
                    acc[i][j] = fmaf(av_[i], bv_[j], acc[i][j]);
        }
        __syncthreads();
    }

    if (mode == 1) {
        #pragma unroll
        for (int i = 0; i < 4; ++i) {
            int m = m0 + ty * 4 + i;
            float4 v;
            v.x = __builtin_amdgcn_exp2f((acc[i][0] + bias[n0 + tx * 4 + 0]) * PS);
            v.y = __builtin_amdgcn_exp2f((acc[i][1] + bias[n0 + tx * 4 + 1]) * PS);
            v.z = __builtin_amdgcn_exp2f((acc[i][2] + bias[n0 + tx * 4 + 2]) * PS);
            v.w = __builtin_amdgcn_exp2f((acc[i][3] + bias[n0 + tx * 4 + 3]) * PS);
            *reinterpret_cast<float4*>(&Es[(size_t)m * AA + n0 + tx * 4]) = v;
        }
    } else if (mode == 0) {
        #pragma unroll
        for (int i = 0; i < 4; ++i)
            #pragma unroll
            for (int j = 0; j < 4; ++j)
                Cs[tx * 4 + j][ty * 4 + i] =
                    __builtin_amdgcn_exp2f((acc[i][j] + bias[n0 + tx * 4 + j]) * PS);
        __syncthreads();
        int row = tid >> 2, part = tid & 3;
        int bb = m0 >> 8;
        int tstart = (m0 & 255) + part * 16;
        float* dst = &EhT[bb * (AA * TT) + (n0 + row) * TT + tstart];
        #pragma unroll
        for (int q = 0; q < 4; ++q) {
            float4 v = *reinterpret_cast<const float4*>(&Cs[row][part * 16 + q * 4]);
            *reinterpret_cast<float4*>(&dst[q * 4]) = v;
        }
    } else {
        int bb = m0 >> 8;
        #pragma unroll
        for (int i = 0; i < 4; ++i) {
            float p = 0.f;
            #pragma unroll
            for (int j = 0; j < 4; ++j) {
                int n = n0 + tx * 4 + j;
                float x = acc[i][j] + bias[n] + ii[bb * AA + n];
                p = fmaf(iv[n], fast_tanh(x), p);
            }
            Cs[ty * 4 + i][tx] = p;
        }
        __syncthreads();
        if (tid < 64) {
            float s = 0.f;
            #pragma unroll
            for (int k = 0; k < 16; ++k) s += Cs[tid][k];
            ipart[blockIdx.y * 2048 + m0 + tid] = s;
        }
    }
}

// ---------------- k3_fused: intent (blocks 0..7) + slot score/softmax/PV (8..1031) ------
// TGROUP=2: 1024 slot blocks -> 4 blocks/CU -> 32 waves/CU.
// sigma = rcp(1 + Eh*Es); weight over s = exp2(PS*(ymin - y)) / sum, y = sum_a v*sigma
__global__ __launch_bounds__(512) void k3_fused(const float* __restrict__ SO,
                                                const float* __restrict__ EhT,
                                                const float* __restrict__ Es,
                                                const float* __restrict__ sv_g,
                                                const float* __restrict__ ipart,
                                                float* __restrict__ out_cslot,
                                                float* __restrict__ out_cint) {
    const int bid = blockIdx.x;
    const int tid = threadIdx.x;

    __shared__ __align__(8) float est[512][2];
    __shared__ float sv[512];
    __shared__ float yp[2][2][256];
    __shared__ __align__(8) float wlt[256][2];
    __shared__ float redm[2][4];
    __shared__ float reds[2][4];
    __shared__ float redI[256];
    __shared__ float wlI[256];

    if (bid >= 8) {
        const int sb_ = bid - 8;
        const int b = sb_ & 7;          // XCD-affine
        const int t0 = (sb_ >> 3) * 2;
        const int s = tid & 255, ah = tid >> 8;

        // stage Es rows (2 t's, transposed) + sv
        {
            const float* esrc = &Es[(size_t)(b * 256 + t0) * 512];
            int i0 = tid;
            est[i0 & 511][i0 >> 9] = esrc[i0];
            int i1 = tid + 512;
            est[i1 & 511][i1 >> 9] = esrc[i1];
            sv[tid] = sv_g[tid];
        }
        __syncthreads();

        const int abase = ah * 256;
        const float* hp = &EhT[((size_t)b * 512 + abase) * 256 + s];
        float y0 = 0.f, y1 = 0.f;
        for (int a0 = 0; a0 < 256; a0 += 8) {
            float h[8];
            #pragma unroll
            for (int u = 0; u < 8; ++u) h[u] = hp[(a0 + u) * 256];
            #pragma unroll
            for (int u = 0; u < 8; ++u) {
                int a = abase + a0 + u;
                float2 e2 = *reinterpret_cast<const float2*>(&est[a][0]);
                float v = sv[a];
                float x0 = fmaf(h[u], e2.x, 1.0f);
                y0 = fmaf(v, __builtin_amdgcn_rcpf(x0), y0);
                float x1 = fmaf(h[u], e2.y, 1.0f);
                y1 = fmaf(v, __builtin_amdgcn_rcpf(x1), y1);
            }
        }
        yp[ah][0][s] = y0; yp[ah][1][s] = y1;
        __syncthreads();

        // softmax: ah-group q owns t-row q over its 256 s-threads (4 waves each)
        const int q = ah;
        const int wg = (tid >> 6) & 3;
        float y = yp[0][q][s] + yp[1][q][s];
        float mn = y;
        #pragma unroll
        for (int off = 1; off < 64; off <<= 1)
            mn = fminf(mn, __shfl_xor(mn, off));
        if ((tid & 63) == 0) redm[q][wg] = mn;
        __syncthreads();
        mn = fminf(fminf(redm[q][0], redm[q][1]), fminf(redm[q][2], redm[q][3]));
        float e = __builtin_amdgcn_exp2f(PS * (mn - y));
        float sm = e;
        #pragma unroll
        for (int off = 1; off < 64; off <<= 1)
            sm += __shfl_xor(sm, off);
        if ((tid & 63) == 0) reds[q][wg] = sm;
        __syncthreads();
        sm = (reds[q][0] + reds[q][1]) + (reds[q][2] + reds[q][3]);
        wlt[s][q] = e * __builtin_amdgcn_rcpf(sm);
        __syncthreads();

        // PV: thread owns d = tid, 2 t-rows
        const int d = tid;
        const float* sop = &SO[(size_t)b * 256 * 512 + d];
        float c0 = 0.f, c1 = 0.f;
        for (int s0 = 0; s0 < 256; s0 += 4) {
            float so[4];
            #pragma unroll
            for (int u = 0; u < 4; ++u) so[u] = sop[(s0 + u) * 512];
            #pragma unroll
            for (int u = 0; u < 4; ++u) {
                float2 w2 = *reinterpret_cast<const float2*>(&wlt[s0 + u][0]);
                c0 = fmaf(w2.x, so[u], c0);
                c1 = fmaf(w2.y, so[u], c1);
            }
        }
        float* op = &out_cslot[((size_t)(b * 256 + t0)) * 512 + d];
        op[0] = c0; op[512] = c1;
    } else {
        // ---- intent path (blocks 0..7, dispatched first -> no tail) ----
        const int b = bid;
        float sc = 0.f;
        if (tid < 256) {
            #pragma unroll
            for (int nb = 0; nb < 8; ++nb) sc += ipart[nb * 2048 + b * 256 + tid];
            redI[tid] = sc;
        }
        __syncthreads();
        for (int off = 128; off > 0; off >>= 1) {
            if (tid < off) redI[tid] = fmaxf(redI[tid], redI[tid + off]);
            __syncthreads();
        }
        float mx = redI[0];
        __syncthreads();
        float e = 0.f;
        if (tid < 256) { e = __builtin_amdgcn_exp2f((sc - mx) * LOG2E); redI[tid] = e; }
        __syncthreads();
        for (int off = 128; off > 0; off >>= 1) {
            if (tid < off) redI[tid] += redI[tid + off];
            __syncthreads();
        }
        if (tid < 256) wlI[tid] = e * __builtin_amdgcn_rcpf(redI[0]);
        __syncthreads();
        const int d = tid;
        float c = 0.f;
        const float* sop = &SO[(size_t)b * 256 * 512 + d];
        for (int s0 = 0; s0 < 256; s0 += 4) {
            float so[4];
            #pragma unroll
            for (int u = 0; u < 4; ++u) so[u] = sop[(s0 + u) * 512];
            #pragma unroll
            for (int u = 0; u < 4; ++u) c = fmaf(wlI[s0 + u], so[u], c);
        }
        out_cint[(size_t)b * 512 + d] = c;
    }
}

extern "C" void kernel_launch(void* const* d_in, const int* in_sizes, int n_in,
                              void* d_out, int out_size, void* d_ws, size_t ws_size,
                              hipStream_t stream) {
    const float* SO  = (const float*)d_in[0];
    const float* FS  = (const float*)d_in[1];
    const float* IV  = (const float*)d_in[2];
    const float* Wih = (const float*)d_in[3];
    const float* bih = (const float*)d_in[4];
    const float* Wii = (const float*)d_in[5];
    const float* bii = (const float*)d_in[6];
    const float* SV  = (const float*)d_in[7];
    const float* Wsh = (const float*)d_in[8];
    const float* bsh = (const float*)d_in[9];
    const float* Wsi = (const float*)d_in[10];
    const float* bsi = (const float*)d_in[11];

    float* ws    = (float*)d_ws;
    float* EhT   = ws;                 // [8][512][256]  exp2'd   1,048,576 f
    float* Es    = ws + 1048576;       // [2048][512]    exp2'd   1,048,576 f
    float* ii    = ws + 2097152;       // [8][512]                4,096 f
    float* ipart = ws + 2101248;       // [16][2048]              32,768 f (8 used)
    ushort* Ast  = (ushort*)(ws + 2134016);  // [2048][1024] bf16
    ushort* Wt   = (ushort*)(ws + 3182592);  // [1536][1024] bf16
    const size_t NEED = (size_t)3969024 * 4;

    float* out_cslot = (float*)d_out;
    float* out_cint  = out_cslot + BB * TT * DD;

    if (ws_size >= NEED) {
        prep<<<1808, 256, 0, stream>>>(SO, Ast, Wsh, Wsi, Wih, Wt, FS, Wii, bii, ii);
        gemm_mfma<<<dim3(16, 12), 256, 0, stream>>>(Ast, Wt, bsh, bsi, bih, ii, IV,
                                                    EhT, Es, ipart);
        k3_fused<<<1032, 512, 0, stream>>>(SO, EhT, Es, SV, ipart, out_cslot, out_cint);
    } else {
        k0_ii<<<dim3(BB, 2), 256, 0, stream>>>(FS, Wii, bii, ii);
        k1_gemm_old<<<dim3(32, 8, 3), 256, 0, stream>>>(SO, Wsh, bsh, Wsi, bsi, Wih, bih,
                                                        ii, IV, EhT, Es, ipart);
        k3_fused<<<1032, 512, 0, stream>>>(SO, EhT, Es, SV, ipart, out_cslot, out_cint);
    }
}

// Round 9
// 104.516 us; speedup vs baseline: 1.3214x; 1.0843x over previous
//
#include <hip/hip_runtime.h>

#define BB 8
#define TT 256
#define DD 512
#define AA 512

#define PS 2.8853900817779268f   // 2*log2(e)
#define LOG2E 1.4426950408889634f

typedef __attribute__((ext_vector_type(8))) short short8;
typedef __attribute__((ext_vector_type(4))) float f32x4;

__device__ __forceinline__ float fast_tanh(float x) {
    float e = __builtin_amdgcn_exp2f(x * PS);
    float r = __builtin_amdgcn_rcpf(1.0f + e);
    return fmaf(-2.0f, r, 1.0f);
}

__device__ __forceinline__ ushort f2bf(float x) {
    uint u = __float_as_uint(x);
    uint r = (u + 0x7fffu + ((u >> 16) & 1u)) >> 16;  // RNE
    return (ushort)r;
}
__device__ __forceinline__ float bf2f(ushort h) {
    return __uint_as_float(((uint)h) << 16);
}

// ---------------- prep: k0 (blocks 0..15) + conv_W (16..783) + conv_A (784..1807) --------
__global__ __launch_bounds__(256) void prep(const float* __restrict__ SO,
                                            ushort* __restrict__ Ast,
                                            const float* __restrict__ Wsh,
                                            const float* __restrict__ Wsi,
                                            const float* __restrict__ Wih,
                                            ushort* __restrict__ Wt,
                                            const float* __restrict__ fs_g,
                                            const float* __restrict__ Wii,
                                            const float* __restrict__ bii,
                                            float* __restrict__ ii) {
    const int bid = blockIdx.x;
    const int tid = threadIdx.x;
    __shared__ float T[32][33];
    __shared__ float fs[DD];

    if (bid < 16) {
        int b = bid >> 1, half = bid & 1;
        int a = half * 256 + tid;
        fs[tid]       = fs_g[b * DD + tid];
        fs[tid + 256] = fs_g[b * DD + tid + 256];
        __syncthreads();
        float acc = bii[a];
        #pragma unroll 8
        for (int d = 0; d < DD; ++d)
            acc = fmaf(fs[d], Wii[(size_t)d * AA + a], acc);
        ii[b * AA + a] = acc;
    } else if (bid < 784) {
        int lbid = bid - 16;
        int z = lbid >> 8;
        int rem = lbid & 255;
        const float* W = (z == 0) ? Wsh : (z == 1) ? Wsi : Wih;
        int k0 = (rem & 15) * 32, n0 = (rem >> 4) * 32;
        int tx = tid & 31, ty = tid >> 5;
        #pragma unroll
        for (int r = 0; r < 4; ++r) {
            int kl = ty * 4 + r;
            T[kl][tx] = W[(size_t)(k0 + kl) * 512 + n0 + tx];
        }
        __syncthreads();
        size_t nbase = (size_t)z * 512 + n0;
        #pragma unroll
        for (int r = 0; r < 4; ++r) {
            int nl = ty * 4 + r;
            float v = T[tx][nl];
            ushort hi = f2bf(v);
            ushort lo = f2bf(v - bf2f(hi));
            Wt[(nbase + nl) * 1024 + k0 + tx]       = hi;
            Wt[(nbase + nl) * 1024 + 512 + k0 + tx] = lo;
        }
    } else {
        int qid = (bid - 784) * 256 + tid;
        int m = qid >> 7;
        int k4 = (qid & 127) * 4;
        float4 v = *reinterpret_cast<const float4*>(&SO[(size_t)m * 512 + k4]);
        ushort4 hi, lo;
        hi.x = f2bf(v.x); lo.x = f2bf(v.x - bf2f(hi.x));
        hi.y = f2bf(v.y); lo.y = f2bf(v.y - bf2f(hi.y));
        hi.z = f2bf(v.z); lo.z = f2bf(v.z - bf2f(hi.z));
        hi.w = f2bf(v.w); lo.w = f2bf(v.w - bf2f(hi.w));
        *reinterpret_cast<ushort4*>(&Ast[(size_t)m * 1024 + k4])       = hi;
        *reinterpret_cast<ushort4*>(&Ast[(size_t)m * 1024 + 512 + k4]) = lo;
    }
}

// ---------------- gemm_mfma: 128x128 tile, BK=32, LDS double-buffer (proven) -------------
__global__ __launch_bounds__(256) void gemm_mfma(
    const ushort* __restrict__ Ast, const ushort* __restrict__ Wt,
    const float* __restrict__ bsh, const float* __restrict__ bsi,
    const float* __restrict__ bih,
    const float* __restrict__ ii, const float* __restrict__ iv,
    float* __restrict__ EhT, float* __restrict__ Es, float* __restrict__ ipart) {
    __shared__ __align__(16) ushort Al[2][128 * 32];
    __shared__ __align__(16) ushort Bl[2][128 * 32];
    const int tid = threadIdx.x;
    const int wave = tid >> 6, lane = tid & 63;
    const int wr = wave >> 1, wc = wave & 1;
    const int m0 = blockIdx.x * 128;
    const int by = blockIdx.y;
    const int l15 = lane & 15, kb = lane >> 4;

    f32x4 acc[4][4] = {};

    const char* Ab = reinterpret_cast<const char*>(Ast);
    const char* Bb = reinterpret_cast<const char*>(Wt);
    char* AlB = reinterpret_cast<char*>(&Al[0][0]);
    char* BlB = reinterpret_cast<char*>(&Bl[0][0]);

    const int srow  = tid >> 1;
    const int sslot = (tid & 1) * 2;
    const int swz   = (srow >> 1) & 3;
    const int lw0 = srow * 64 + ((sslot    ) ^ swz) * 16;
    const int lw1 = srow * 64 + ((sslot + 1) ^ swz) * 16;
    const char* agp = Ab + (size_t)(m0 + srow) * 2048 + sslot * 16;
    const char* bgp = Bb + (size_t)(by * 128 + srow) * 2048 + sslot * 16;

    int aro[4], bro[4];
    #pragma unroll
    for (int i = 0; i < 4; ++i) {
        int ra = wr * 64 + i * 16 + l15;
        aro[i] = ra * 64 + ((kb ^ ((ra >> 1) & 3)) * 16);
        int rb = wc * 64 + i * 16 + l15;
        bro[i] = rb * 64 + ((kb ^ ((rb >> 1) & 3)) * 16);
    }

    #define ABYTE(k0) (((k0) < 1024 ? (k0) : (k0) - 1024) * 2)
    #define BBYTE(k0) (((k0) < 512 ? (k0) : (k0) - 512) * 2)

    {
        short8 a0 = *reinterpret_cast<const short8*>(agp + ABYTE(0));
        short8 a1 = *reinterpret_cast<const short8*>(agp + ABYTE(0) + 16);
        short8 b0 = *reinterpret_cast<const short8*>(bgp + BBYTE(0));
        short8 b1 = *reinterpret_cast<const short8*>(bgp + BBYTE(0) + 16);
        *reinterpret_cast<short8*>(AlB + lw0) = a0;
        *reinterpret_cast<short8*>(AlB + lw1) = a1;
        *reinterpret_cast<short8*>(BlB + lw0) = b0;
        *reinterpret_cast<short8*>(BlB + lw1) = b1;
    }
    __syncthreads();

    int cur = 0;
    for (int it = 0; it < 48; ++it) {
        short8 a0, a1, b0, b1;
        const bool pf = (it + 1 < 48);
        if (pf) {
            int k0 = (it + 1) * 32;
            int ab = ABYTE(k0), bb = BBYTE(k0);
            a0 = *reinterpret_cast<const short8*>(agp + ab);
            a1 = *reinterpret_cast<const short8*>(agp + ab + 16);
            b0 = *reinterpret_cast<const short8*>(bgp + bb);
            b1 = *reinterpret_cast<const short8*>(bgp + bb + 16);
        }
        const char* Ac = AlB + cur * 8192;
        const char* Bc = BlB + cur * 8192;
        short8 af[4], bf[4];
        #pragma unroll
        for (int i = 0; i < 4; ++i) {
            af[i] = *reinterpret_cast<const short8*>(Ac + aro[i]);
            bf[i] = *reinterpret_cast<const short8*>(Bc + bro[i]);
        }
        #pragma unroll
        for (int i = 0; i < 4; ++i)
            #pragma unroll
            for (int j = 0; j < 4; ++j)
                acc[i][j] = __builtin_amdgcn_mfma_f32_16x16x32_bf16(
                    af[i], bf[j], acc[i][j], 0, 0, 0);
        if (pf) {
            char* An = AlB + (cur ^ 1) * 8192;
            char* Bn = BlB + (cur ^ 1) * 8192;
            *reinterpret_cast<short8*>(An + lw0) = a0;
            *reinterpret_cast<short8*>(An + lw1) = a1;
            *reinterpret_cast<short8*>(Bn + lw0) = b0;
            *reinterpret_cast<short8*>(Bn + lw1) = b1;
        }
        __syncthreads();
        cur ^= 1;
    }

    const int b = m0 >> 8;
    const int region = by >> 2;
    if (region == 0) {
        #pragma unroll
        for (int i = 0; i < 4; ++i) {
            int t0 = (m0 & 255) + wr * 64 + i * 16 + kb * 4;
            #pragma unroll
            for (int j = 0; j < 4; ++j) {
                int n = by * 128 + wc * 64 + j * 16 + l15;
                float bbv = bsh[n];
                float4 v;
                v.x = __builtin_amdgcn_exp2f((acc[i][j][0] + bbv) * PS);
                v.y = __builtin_amdgcn_exp2f((acc[i][j][1] + bbv) * PS);
                v.z = __builtin_amdgcn_exp2f((acc[i][j][2] + bbv) * PS);
                v.w = __builtin_amdgcn_exp2f((acc[i][j][3] + bbv) * PS);
                *reinterpret_cast<float4*>(&EhT[((size_t)b * 512 + n) * 256 + t0]) = v;
            }
        }
    } else if (region == 1) {
        #pragma unroll
        for (int i = 0; i < 4; ++i) {
            #pragma unroll
            for (int j = 0; j < 4; ++j) {
                int n = (by - 4) * 128 + wc * 64 + j * 16 + l15;
                float bbv = bsi[n];
                #pragma unroll
                for (int r = 0; r < 4; ++r) {
                    int m = m0 + wr * 64 + i * 16 + kb * 4 + r;
                    Es[(size_t)m * 512 + n] = __builtin_amdgcn_exp2f((acc[i][j][r] + bbv) * PS);
                }
            }
        }
    } else {
        int slot = (by - 8) * 2 + wc;
        #pragma unroll
        for (int i = 0; i < 4; ++i) {
            float p0 = 0.f, p1 = 0.f, p2 = 0.f, p3 = 0.f;
            #pragma unroll
            for (int j = 0; j < 4; ++j) {
                int n = (by - 8) * 128 + wc * 64 + j * 16 + l15;
                float add = bih[n] + ii[b * 512 + n];
                float w = iv[n];
                p0 = fmaf(w, fast_tanh(acc[i][j][0] + add), p0);
                p1 = fmaf(w, fast_tanh(acc[i][j][1] + add), p1);
                p2 = fmaf(w, fast_tanh(acc[i][j][2] + add), p2);
                p3 = fmaf(w, fast_tanh(acc[i][j][3] + add), p3);
            }
            #pragma unroll
            for (int off = 1; off < 16; off <<= 1) {
                p0 += __shfl_xor(p0, off);
                p1 += __shfl_xor(p1, off);
                p2 += __shfl_xor(p2, off);
                p3 += __shfl_xor(p3, off);
            }
            int mb = m0 + wr * 64 + i * 16 + kb * 4;
            if (l15 == 0) ipart[slot * 2048 + mb + 0] = p0;
            if (l15 == 1) ipart[slot * 2048 + mb + 1] = p1;
            if (l15 == 2) ipart[slot * 2048 + mb + 2] = p2;
            if (l15 == 3) ipart[slot * 2048 + mb + 3] = p3;
        }
    }
}

// ---------------- fallback fp32 GEMM path ----------------
#define TS 64
#define KS 16
#define LPAD 72

__global__ __launch_bounds__(256) void k0_ii(const float* __restrict__ fs_g,
                                             const float* __restrict__ Wii,
                                             const float* __restrict__ bii,
                                             float* __restrict__ ii) {
    int b = blockIdx.x, tid = threadIdx.x;
    int a = blockIdx.y * 256 + tid;
    __shared__ float fs[DD];
    fs[tid]       = fs_g[b * DD + tid];
    fs[tid + 256] = fs_g[b * DD + tid + 256];
    __syncthreads();
    float acc = bii[a];
    #pragma unroll 8
    for (int d = 0; d < DD; ++d)
        acc = fmaf(fs[d], Wii[(size_t)d * AA + a], acc);
    ii[b * AA + a] = acc;
}

__global__ __launch_bounds__(256) void k1_gemm_old(
    const float* __restrict__ SO,
    const float* __restrict__ Wsh, const float* __restrict__ bsh,
    const float* __restrict__ Wsi, const float* __restrict__ bsi,
    const float* __restrict__ Wih, const float* __restrict__ bih,
    const float* __restrict__ ii, const float* __restrict__ iv,
    float* __restrict__ EhT, float* __restrict__ Es, float* __restrict__ ipart) {
    const int mode = blockIdx.z;
    const float* W;
    const float* bias;
    if (mode == 0)      { W = Wsh; bias = bsh; }
    else if (mode == 1) { W = Wsi; bias = bsi; }
    else                { W = Wih; bias = bih; }

    const int m0 = blockIdx.x * TS;
    const int n0 = blockIdx.y * TS;
    const int tid = threadIdx.x;
    const int tx = tid & 15, ty = tid >> 4;

    __shared__ __align__(16) float As[KS][LPAD];
    __shared__ __align__(16) float Bs[KS][LPAD];
    __shared__ __align__(16) float Cs[TS][LPAD];

    float acc[4][4] = {};
    const int arow = tid >> 2;
    const int akc  = (tid & 3) * 4;
    const int brw  = tid >> 4;
    const int bnc  = (tid & 15) * 4;

    for (int k0 = 0; k0 < DD; k0 += KS) {
        float4 av = *reinterpret_cast<const float4*>(&SO[(m0 + arow) * DD + k0 + akc]);
        As[akc + 0][arow] = av.x;
        As[akc + 1][arow] = av.y;
        As[akc + 2][arow] = av.z;
        As[akc + 3][arow] = av.w;
        float4 bv = *reinterpret_cast<const float4*>(&W[(k0 + brw) * AA + n0 + bnc]);
        *reinterpret_cast<float4*>(&Bs[brw][bnc]) = bv;
        __syncthreads();
        #pragma unroll
        for (int kk = 0; kk < KS; ++kk) {
            float4 a4 = *reinterpret_cast<const float4*>(&As[kk][ty * 4]);
            float4 b4 = *reinterpret_cast<const float4*>(&Bs[kk][tx * 4]);
            float av_[4] = {a4.x, a4.y, a4.z, a4.w};
            float bv_[4] = {b4.x, b4.y, b4.z, b4.w};
            #pragma unroll
            for (int i = 0; i < 4; ++i)
                #pragma unroll
                for (int j = 0; j < 4; ++j)
                    acc[i][j] = fmaf(av_[i], bv_[j], acc[i][j]);
        }
        __syncthreads();
    }

    if (mode == 1) {
        #pragma unroll
        for (int i = 0; i < 4; ++i) {
            int m = m0 + ty * 4 + i;
            float4 v;
            v.x = __builtin_amdgcn_exp2f((acc[i][0] + bias[n0 + tx * 4 + 0]) * PS);
            v.y = __builtin_amdgcn_exp2f((acc[i][1] + bias[n0 + tx * 4 + 1]) * PS);
            v.z = __builtin_amdgcn_exp2f((acc[i][2] + bias[n0 + tx * 4 + 2]) * PS);
            v.w = __builtin_amdgcn_exp2f((acc[i][3] + bias[n0 + tx * 4 + 3]) * PS);
            *reinterpret_cast<float4*>(&Es[(size_t)m * AA + n0 + tx * 4]) = v;
        }
    } else if (mode == 0) {
        #pragma unroll
        for (int i = 0; i < 4; ++i)
            #pragma unroll
            for (int j = 0; j < 4; ++j)
                Cs[tx * 4 + j][ty * 4 + i] =
                    __builtin_amdgcn_exp2f((acc[i][j] + bias[n0 + tx * 4 + j]) * PS);
        __syncthreads();
        int row = tid >> 2, part = tid & 3;
        int bb = m0 >> 8;
        int tstart = (m0 & 255) + part * 16;
        float* dst = &EhT[bb * (AA * TT) + (n0 + row) * TT + tstart];
        #pragma unroll
        for (int q = 0; q < 4; ++q) {
            float4 v = *reinterpret_cast<const float4*>(&Cs[row][part * 16 + q * 4]);
            *reinterpret_cast<float4*>(&dst[q * 4]) = v;
        }
    } else {
        int bb = m0 >> 8;
        #pragma unroll
        for (int i = 0; i < 4; ++i) {
            float p = 0.f;
            #pragma unroll
            for (int j = 0; j < 4; ++j) {
                int n = n0 + tx * 4 + j;
                float x = acc[i][j] + bias[n] + ii[bb * AA + n];
                p = fmaf(iv[n], fast_tanh(x), p);
            }
            Cs[ty * 4 + i][tx] = p;
        }
        __syncthreads();
        if (tid < 64) {
            float s = 0.f;
            #pragma unroll
            for (int k = 0; k < 16; ++k) s += Cs[tid][k];
            ipart[blockIdx.y * 2048 + m0 + tid] = s;
        }
    }
}

// ---------------- k3_fused: intent (blocks 0..7) + slot TG4xSG2 (8..519) -----------------
// Each slot block: b, t0..t0+3. Thread = (s-pair sp, a-quarter ah). Per a:
// 1 float2 h (global) + 1 b128 est (4 t's, broadcast) + 1/4 b128 sv -> 8 rcp + 16 fma.
__global__ __launch_bounds__(512) void k3_fused(const float* __restrict__ SO,
                                                const float* __restrict__ EhT,
                                                const float* __restrict__ Es,
                                                const float* __restrict__ sv_g,
                                                const float* __restrict__ ipart,
                                                float* __restrict__ out_cslot,
                                                float* __restrict__ out_cint,
                                                int npart) {
    const int bid = blockIdx.x;
    const int tid = threadIdx.x;

    __shared__ __align__(16) float est[512][4];   // [a][q]
    __shared__ __align__(16) float sv[512];
    __shared__ __align__(8)  float yp[4][4][256]; // [ah][q][s]
    __shared__ __align__(16) float wlt[256][4];
    __shared__ float redm[4][2];
    __shared__ float reds[4][2];
    __shared__ float redI[256];
    __shared__ float wlI[256];

    if (bid >= 8) {
        const int sb_ = bid - 8;
        const int b = sb_ & 7;          // XCD-affine
        const int t0 = (sb_ >> 3) * 4;
        const int sp = tid & 127;       // s-pair index: s = 2*sp, 2*sp+1
        const int ah = tid >> 7;        // 0..3, a-quarter
        const int abase = ah * 128;

        // stage est (transposed gather) + sv
        {
            const float* esrc = &Es[(size_t)(b * 256 + t0) * 512];
            #pragma unroll
            for (int i = tid; i < 2048; i += 512) est[i & 511][i >> 9] = esrc[i];
            sv[tid] = sv_g[tid];
        }
        __syncthreads();

        // ---- score: 128 a x 4 t x 2 s per thread ----
        const float* hp = &EhT[((size_t)b * 512 + abase) * 256 + 2 * sp];
        float a00=0.f,a01=0.f,a10=0.f,a11=0.f,a20=0.f,a21=0.f,a30=0.f,a31=0.f;
        for (int a0 = 0; a0 < 128; a0 += 4) {
            float4 v4 = *reinterpret_cast<const float4*>(&sv[abase + a0]);
            float2 h[4];
            #pragma unroll
            for (int u = 0; u < 4; ++u)
                h[u] = *reinterpret_cast<const float2*>(&hp[(a0 + u) * 256]);
            #pragma unroll
            for (int u = 0; u < 4; ++u) {
                float4 e4 = *reinterpret_cast<const float4*>(&est[abase + a0 + u][0]);
                float vv = (u == 0) ? v4.x : (u == 1) ? v4.y : (u == 2) ? v4.z : v4.w;
                float hx = h[u].x, hy = h[u].y;
                a00 = fmaf(vv, __builtin_amdgcn_rcpf(fmaf(hx, e4.x, 1.f)), a00);
                a01 = fmaf(vv, __builtin_amdgcn_rcpf(fmaf(hy, e4.x, 1.f)), a01);
                a10 = fmaf(vv, __builtin_amdgcn_rcpf(fmaf(hx, e4.y, 1.f)), a10);
                a11 = fmaf(vv, __builtin_amdgcn_rcpf(fmaf(hy, e4.y, 1.f)), a11);
                a20 = fmaf(vv, __builtin_amdgcn_rcpf(fmaf(hx, e4.z, 1.f)), a20);
                a21 = fmaf(vv, __builtin_amdgcn_rcpf(fmaf(hy, e4.z, 1.f)), a21);
                a30 = fmaf(vv, __builtin_amdgcn_rcpf(fmaf(hx, e4.w, 1.f)), a30);
                a31 = fmaf(vv, __builtin_amdgcn_rcpf(fmaf(hy, e4.w, 1.f)), a31);
            }
        }
        *reinterpret_cast<float2*>(&yp[ah][0][2 * sp]) = make_float2(a00, a01);
        *reinterpret_cast<float2*>(&yp[ah][1][2 * sp]) = make_float2(a10, a11);
        *reinterpret_cast<float2*>(&yp[ah][2][2 * sp]) = make_float2(a20, a21);
        *reinterpret_cast<float2*>(&yp[ah][3][2 * sp]) = make_float2(a30, a31);
        __syncthreads();

        // ---- softmax: group g = ah owns t-row g; 128 threads handle s=L and s=L+128 ----
        const int g = ah;
        const int L = sp;
        const int w2 = (tid >> 6) & 1;
        float yL = (yp[0][g][L]       + yp[1][g][L])       + (yp[2][g][L]       + yp[3][g][L]);
        float yH = (yp[0][g][L + 128] + yp[1][g][L + 128]) + (yp[2][g][L + 128] + yp[3][g][L + 128]);
        float mn = fminf(yL, yH);
        #pragma unroll
        for (int off = 1; off < 64; off <<= 1)
            mn = fminf(mn, __shfl_xor(mn, off));
        if ((tid & 63) == 0) redm[g][w2] = mn;
        __syncthreads();
        mn = fminf(redm[g][0], redm[g][1]);
        float eL = __builtin_amdgcn_exp2f(PS * (mn - yL));
        float eH = __builtin_amdgcn_exp2f(PS * (mn - yH));
        float sm = eL + eH;
        #pragma unroll
        for (int off = 1; off < 64; off <<= 1)
            sm += __shfl_xor(sm, off);
        if ((tid & 63) == 0) reds[g][w2] = sm;
        __syncthreads();
        sm = reds[g][0] + reds[g][1];
        float rs = __builtin_amdgcn_rcpf(sm);
        wlt[L][g]       = eL * rs;
        wlt[L + 128][g] = eH * rs;
        __syncthreads();

        // ---- PV: thread owns d = tid, 4 t-rows ----
        const int d = tid;
        const float* sop = &SO[(size_t)b * 256 * 512 + d];
        float c0 = 0.f, c1 = 0.f, c2 = 0.f, c3 = 0.f;
        for (int s0 = 0; s0 < 256; s0 += 4) {
            float so[4];
            #pragma unroll
            for (int u = 0; u < 4; ++u) so[u] = sop[(s0 + u) * 512];
            #pragma unroll
            for (int u = 0; u < 4; ++u) {
                float4 w4 = *reinterpret_cast<const float4*>(&wlt[s0 + u][0]);
                c0 = fmaf(w4.x, so[u], c0);
                c1 = fmaf(w4.y, so[u], c1);
                c2 = fmaf(w4.z, so[u], c2);
                c3 = fmaf(w4.w, so[u], c3);
            }
        }
        float* op = &out_cslot[((size_t)(b * 256 + t0)) * 512 + d];
        op[0] = c0; op[512] = c1; op[1024] = c2; op[1536] = c3;
    } else {
        // ---- intent path (blocks 0..7, dispatched first -> no tail) ----
        const int b = bid;
        float sc = 0.f;
        if (tid < 256) {
            for (int nb = 0; nb < npart; ++nb) sc += ipart[nb * 2048 + b * 256 + tid];
            redI[tid] = sc;
        }
        __syncthreads();
        for (int off = 128; off > 0; off >>= 1) {
            if (tid < off) redI[tid] = fmaxf(redI[tid], redI[tid + off]);
            __syncthreads();
        }
        float mx = redI[0];
        __syncthreads();
        float e = 0.f;
        if (tid < 256) { e = __builtin_amdgcn_exp2f((sc - mx) * LOG2E); redI[tid] = e; }
        __syncthreads();
        for (int off = 128; off > 0; off >>= 1) {
            if (tid < off) redI[tid] += redI[tid + off];
            __syncthreads();
        }
        if (tid < 256) wlI[tid] = e * __builtin_amdgcn_rcpf(redI[0]);
        __syncthreads();
        const int d = tid;
        float c = 0.f;
        const float* sop = &SO[(size_t)b * 256 * 512 + d];
        for (int s0 = 0; s0 < 256; s0 += 4) {
            float so[4];
            #pragma unroll
            for (int u = 0; u < 4; ++u) so[u] = sop[(s0 + u) * 512];
            #pragma unroll
            for (int u = 0; u < 4; ++u) c = fmaf(wlI[s0 + u], so[u], c);
        }
        out_cint[(size_t)b * 512 + d] = c;
    }
}

extern "C" void kernel_launch(void* const* d_in, const int* in_sizes, int n_in,
                              void* d_out, int out_size, void* d_ws, size_t ws_size,
                              hipStream_t stream) {
    const float* SO  = (const float*)d_in[0];
    const float* FS  = (const float*)d_in[1];
    const float* IV  = (const float*)d_in[2];
    const float* Wih = (const float*)d_in[3];
    const float* bih = (const float*)d_in[4];
    const float* Wii = (const float*)d_in[5];
    const float* bii = (const float*)d_in[6];
    const float* SV  = (const float*)d_in[7];
    const float* Wsh = (const float*)d_in[8];
    const float* bsh = (const float*)d_in[9];
    const float* Wsi = (const float*)d_in[10];
    const float* bsi = (const float*)d_in[11];

    float* ws    = (float*)d_ws;
    float* EhT   = ws;                 // [8][512][256]  exp2'd   1,048,576 f
    float* Es    = ws + 1048576;       // [2048][512]    exp2'd   1,048,576 f
    float* ii    = ws + 2097152;       // [8][512]                4,096 f
    float* ipart = ws + 2101248;       // [16][2048]              32,768 f (8 used)
    ushort* Ast  = (ushort*)(ws + 2134016);  // [2048][1024] bf16
    ushort* Wt   = (ushort*)(ws + 3182592);  // [1536][1024] bf16
    const size_t NEED = (size_t)3969024 * 4;

    float* out_cslot = (float*)d_out;
    float* out_cint  = out_cslot + BB * TT * DD;

    if (ws_size >= NEED) {
        prep<<<1808, 256, 0, stream>>>(SO, Ast, Wsh, Wsi, Wih, Wt, FS, Wii, bii, ii);
        gemm_mfma<<<dim3(16, 12), 256, 0, stream>>>(Ast, Wt, bsh, bsi, bih, ii, IV,
                                                    EhT, Es, ipart);
        k3_fused<<<520, 512, 0, stream>>>(SO, EhT, Es, SV, ipart, out_cslot, out_cint, 8);
    } else {
        k0_ii<<<dim3(BB, 2), 256, 0, stream>>>(FS, Wii, bii, ii);
        k1_gemm_old<<<dim3(32, 8, 3), 256, 0, stream>>>(SO, Wsh, bsh, Wsi, bsi, Wih, bih,
                                                        ii, IV, EhT, Es, ipart);
        k3_fused<<<520, 512, 0, stream>>>(SO, EhT, Es, SV, ipart, out_cslot, out_cint, 8);
    }
}

// Round 10
// 93.331 us; speedup vs baseline: 1.4798x; 1.1198x over previous
//
#include <hip/hip_runtime.h>

#define BB 8
#define TT 256
#define DD 512
#define AA 512

#define PS 2.8853900817779268f   // 2*log2(e)
#define LOG2E 1.4426950408889634f

typedef __attribute__((ext_vector_type(8))) short short8;
typedef __attribute__((ext_vector_type(4))) float f32x4;

__device__ __forceinline__ float fast_tanh(float x) {
    float e = __builtin_amdgcn_exp2f(x * PS);
    float r = __builtin_amdgcn_rcpf(1.0f + e);
    return fmaf(-2.0f, r, 1.0f);
}

__device__ __forceinline__ ushort f2bf(float x) {
    uint u = __float_as_uint(x);
    uint r = (u + 0x7fffu + ((u >> 16) & 1u)) >> 16;  // RNE
    return (ushort)r;
}
__device__ __forceinline__ float bf2f(ushort h) {
    return __uint_as_float(((uint)h) << 16);
}

#define ABYTE(k0) (((k0) < 1024 ? (k0) : (k0) - 1024) * 2)
#define BBYTE(k0) (((k0) < 512 ? (k0) : (k0) - 512) * 2)

// ---------------- prep: k0 (blocks 0..15) + conv_W (16..783) + conv_A (784..1807) --------
__global__ __launch_bounds__(256) void prep(const float* __restrict__ SO,
                                            ushort* __restrict__ Ast,
                                            const float* __restrict__ Wsh,
                                            const float* __restrict__ Wsi,
                                            const float* __restrict__ Wih,
                                            ushort* __restrict__ Wt,
                                            const float* __restrict__ fs_g,
                                            const float* __restrict__ Wii,
                                            const float* __restrict__ bii,
                                            float* __restrict__ ii) {
    const int bid = blockIdx.x;
    const int tid = threadIdx.x;
    __shared__ float T[32][33];
    __shared__ float fs[DD];

    if (bid < 16) {
        int b = bid >> 1, half = bid & 1;
        int a = half * 256 + tid;
        fs[tid]       = fs_g[b * DD + tid];
        fs[tid + 256] = fs_g[b * DD + tid + 256];
        __syncthreads();
        float acc = bii[a];
        #pragma unroll 8
        for (int d = 0; d < DD; ++d)
            acc = fmaf(fs[d], Wii[(size_t)d * AA + a], acc);
        ii[b * AA + a] = acc;
    } else if (bid < 784) {
        int lbid = bid - 16;
        int z = lbid >> 8;
        int rem = lbid & 255;
        const float* W = (z == 0) ? Wsh : (z == 1) ? Wsi : Wih;
        int k0 = (rem & 15) * 32, n0 = (rem >> 4) * 32;
        int tx = tid & 31, ty = tid >> 5;
        #pragma unroll
        for (int r = 0; r < 4; ++r) {
            int kl = ty * 4 + r;
            T[kl][tx] = W[(size_t)(k0 + kl) * 512 + n0 + tx];
        }
        __syncthreads();
        size_t nbase = (size_t)z * 512 + n0;
        #pragma unroll
        for (int r = 0; r < 4; ++r) {
            int nl = ty * 4 + r;
            float v = T[tx][nl];
            ushort hi = f2bf(v);
            ushort lo = f2bf(v - bf2f(hi));
            Wt[(nbase + nl) * 1024 + k0 + tx]       = hi;
            Wt[(nbase + nl) * 1024 + 512 + k0 + tx] = lo;
        }
    } else {
        int qid = (bid - 784) * 256 + tid;
        int m = qid >> 7;
        int k4 = (qid & 127) * 4;
        float4 v = *reinterpret_cast<const float4*>(&SO[(size_t)m * 512 + k4]);
        ushort4 hi, lo;
        hi.x = f2bf(v.x); lo.x = f2bf(v.x - bf2f(hi.x));
        hi.y = f2bf(v.y); lo.y = f2bf(v.y - bf2f(hi.y));
        hi.z = f2bf(v.z); lo.z = f2bf(v.z - bf2f(hi.z));
        hi.w = f2bf(v.w); lo.w = f2bf(v.w - bf2f(hi.w));
        *reinterpret_cast<ushort4*>(&Ast[(size_t)m * 1024 + k4])       = hi;
        *reinterpret_cast<ushort4*>(&Ast[(size_t)m * 1024 + 512 + k4]) = lo;
    }
}

// ---------------- gemm_mfma: 64x64 tile, BK=64, LDS double-buffer, grid (32,24)=768 ------
// Logical K=1536: [0,512) A-hi x W-hi ; [512,1024) A-lo x W-hi ; [1024,1536) A-hi x W-lo
// by: 0-7 sh -> EhT ; 8-15 si -> Es ; 16-23 ih -> ipart[16][]
__global__ __launch_bounds__(256) void gemm_mfma(
    const ushort* __restrict__ Ast, const ushort* __restrict__ Wt,
    const float* __restrict__ bsh, const float* __restrict__ bsi,
    const float* __restrict__ bih,
    const float* __restrict__ ii, const float* __restrict__ iv,
    float* __restrict__ EhT, float* __restrict__ Es, float* __restrict__ ipart) {
    __shared__ __align__(16) ushort Al[2][64 * 64];
    __shared__ __align__(16) ushort Bl[2][64 * 64];
    const int tid = threadIdx.x;
    const int wave = tid >> 6, lane = tid & 63;
    const int wr = wave >> 1, wc = wave & 1;
    const int m0 = blockIdx.x * 64;
    const int by = blockIdx.y;
    const int n0 = by * 64;
    const int l15 = lane & 15, kb = lane >> 4;

    f32x4 acc[2][2] = {};

    const char* Ab = reinterpret_cast<const char*>(Ast);
    const char* Bb = reinterpret_cast<const char*>(Wt);
    char* AlB = reinterpret_cast<char*>(&Al[0][0]);
    char* BlB = reinterpret_cast<char*>(&Bl[0][0]);

    // staging: thread covers row = tid>>2, slots sslot and sslot+4 (row = 128B = 64 bf16)
    const int srow = tid >> 2, sslot = tid & 3;
    const int lw0 = srow * 128 + (((sslot    ) ^ (srow & 7)) * 16);
    const int lw1 = srow * 128 + (((sslot + 4) ^ (srow & 7)) * 16);
    const char* agp = Ab + (size_t)(m0 + srow) * 2048 + sslot * 16;
    const char* bgp = Bb + (size_t)(n0 + srow) * 2048 + sslot * 16;

    // frag read offsets (within one 8KB buffer)
    int aro[2][2], bro[2][2];
    #pragma unroll
    for (int i = 0; i < 2; ++i) {
        int ra = wr * 32 + i * 16 + l15;
        int rb = wc * 32 + i * 16 + l15;
        #pragma unroll
        for (int kk = 0; kk < 2; ++kk) {
            aro[kk][i] = ra * 128 + (((kk * 4 + kb) ^ (ra & 7)) * 16);
            bro[kk][i] = rb * 128 + (((kk * 4 + kb) ^ (rb & 7)) * 16);
        }
    }

    // prologue: stage k0=0 into buf0
    {
        short8 a0 = *reinterpret_cast<const short8*>(agp + ABYTE(0));
        short8 a1 = *reinterpret_cast<const short8*>(agp + ABYTE(0) + 64);
        short8 b0 = *reinterpret_cast<const short8*>(bgp + BBYTE(0));
        short8 b1 = *reinterpret_cast<const short8*>(bgp + BBYTE(0) + 64);
        *reinterpret_cast<short8*>(AlB + lw0) = a0;
        *reinterpret_cast<short8*>(AlB + lw1) = a1;
        *reinterpret_cast<short8*>(BlB + lw0) = b0;
        *reinterpret_cast<short8*>(BlB + lw1) = b1;
    }
    __syncthreads();

    int cur = 0;
    for (int it = 0; it < 24; ++it) {
        short8 pa0, pa1, pb0, pb1;
        const bool pf = (it + 1 < 24);
        if (pf) {
            int k0 = (it + 1) * 64;
            int ab = ABYTE(k0), bb = BBYTE(k0);
            pa0 = *reinterpret_cast<const short8*>(agp + ab);
            pa1 = *reinterpret_cast<const short8*>(agp + ab + 64);
            pb0 = *reinterpret_cast<const short8*>(bgp + bb);
            pb1 = *reinterpret_cast<const short8*>(bgp + bb + 64);
        }
        const char* Ac = AlB + cur * 8192;
        const char* Bc = BlB + cur * 8192;
        #pragma unroll
        for (int kk = 0; kk < 2; ++kk) {
            short8 af[2], bf[2];
            #pragma unroll
            for (int i = 0; i < 2; ++i) {
                af[i] = *reinterpret_cast<const short8*>(Ac + aro[kk][i]);
                bf[i] = *reinterpret_cast<const short8*>(Bc + bro[kk][i]);
            }
            #pragma unroll
            for (int i = 0; i < 2; ++i)
                #pragma unroll
                for (int j = 0; j < 2; ++j)
                    acc[i][j] = __builtin_amdgcn_mfma_f32_16x16x32_bf16(
                        af[i], bf[j], acc[i][j], 0, 0, 0);
        }
        if (pf) {
            char* An = AlB + (cur ^ 1) * 8192;
            char* Bn = BlB + (cur ^ 1) * 8192;
            *reinterpret_cast<short8*>(An + lw0) = pa0;
            *reinterpret_cast<short8*>(An + lw1) = pa1;
            *reinterpret_cast<short8*>(Bn + lw0) = pb0;
            *reinterpret_cast<short8*>(Bn + lw1) = pb1;
        }
        __syncthreads();
        cur ^= 1;
    }

    const int b = m0 >> 8;
    if (by < 8) {
        #pragma unroll
        for (int i = 0; i < 2; ++i) {
            int t0 = (m0 & 255) + wr * 32 + i * 16 + kb * 4;
            #pragma unroll
            for (int j = 0; j < 2; ++j) {
                int n = n0 + wc * 32 + j * 16 + l15;
                float bbv = bsh[n];
                float4 v;
                v.x = __builtin_amdgcn_exp2f((acc[i][j][0] + bbv) * PS);
                v.y = __builtin_amdgcn_exp2f((acc[i][j][1] + bbv) * PS);
                v.z = __builtin_amdgcn_exp2f((acc[i][j][2] + bbv) * PS);
                v.w = __builtin_amdgcn_exp2f((acc[i][j][3] + bbv) * PS);
                *reinterpret_cast<float4*>(&EhT[((size_t)b * 512 + n) * 256 + t0]) = v;
            }
        }
    } else if (by < 16) {
        #pragma unroll
        for (int i = 0; i < 2; ++i) {
            #pragma unroll
            for (int j = 0; j < 2; ++j) {
                int n = n0 - 512 + wc * 32 + j * 16 + l15;
                float bbv = bsi[n];
                #pragma unroll
                for (int r = 0; r < 4; ++r) {
                    int m = m0 + wr * 32 + i * 16 + kb * 4 + r;
                    Es[(size_t)m * 512 + n] = __builtin_amdgcn_exp2f((acc[i][j][r] + bbv) * PS);
                }
            }
        }
    } else {
        int slot = (by - 16) * 2 + wc;
        #pragma unroll
        for (int i = 0; i < 2; ++i) {
            float p0 = 0.f, p1 = 0.f, p2 = 0.f, p3 = 0.f;
            #pragma unroll
            for (int j = 0; j < 2; ++j) {
                int n = n0 - 1024 + wc * 32 + j * 16 + l15;
                float add = bih[n] + ii[b * 512 + n];
                float w = iv[n];
                p0 = fmaf(w, fast_tanh(acc[i][j][0] + add), p0);
                p1 = fmaf(w, fast_tanh(acc[i][j][1] + add), p1);
                p2 = fmaf(w, fast_tanh(acc[i][j][2] + add), p2);
                p3 = fmaf(w, fast_tanh(acc[i][j][3] + add), p3);
            }
            #pragma unroll
            for (int off = 1; off < 16; off <<= 1) {
                p0 += __shfl_xor(p0, off);
                p1 += __shfl_xor(p1, off);
                p2 += __shfl_xor(p2, off);
                p3 += __shfl_xor(p3, off);
            }
            int mb = m0 + wr * 32 + i * 16 + kb * 4;
            if (l15 == 0) ipart[slot * 2048 + mb + 0] = p0;
            if (l15 == 1) ipart[slot * 2048 + mb + 1] = p1;
            if (l15 == 2) ipart[slot * 2048 + mb + 2] = p2;
            if (l15 == 3) ipart[slot * 2048 + mb + 3] = p3;
        }
    }
}

// ---------------- fallback fp32 GEMM path ----------------
#define TS 64
#define KS 16
#define LPAD 72

__global__ __launch_bounds__(256) void k0_ii(const float* __restrict__ fs_g,
                                             const float* __restrict__ Wii,
                                             const float* __restrict__ bii,
                                             float* __restrict__ ii) {
    int b = blockIdx.x, tid = threadIdx.x;
    int a = blockIdx.y * 256 + tid;
    __shared__ float fs[DD];
    fs[tid]       = fs_g[b * DD + tid];
    fs[tid + 256] = fs_g[b * DD + tid + 256];
    __syncthreads();
    float acc = bii[a];
    #pragma unroll 8
    for (int d = 0; d < DD; ++d)
        acc = fmaf(fs[d], Wii[(size_t)d * AA + a], acc);
    ii[b * AA + a] = acc;
}

__global__ __launch_bounds__(256) void k1_gemm_old(
    const float* __restrict__ SO,
    const float* __restrict__ Wsh, const float* __restrict__ bsh,
    const float* __restrict__ Wsi, const float* __restrict__ bsi,
    const float* __restrict__ Wih, const float* __restrict__ bih,
    const float* __restrict__ ii, const float* __restrict__ iv,
    float* __restrict__ EhT, float* __restrict__ Es, float* __restrict__ ipart) {
    const int mode = blockIdx.z;
    const float* W;
    const float* bias;
    if (mode == 0)      { W = Wsh; bias = bsh; }
    else if (mode == 1) { W = Wsi; bias = bsi; }
    else                { W = Wih; bias = bih; }

    const int m0 = blockIdx.x * TS;
    const int n0 = blockIdx.y * TS;
    const int tid = threadIdx.x;
    const int tx = tid & 15, ty = tid >> 4;

    __shared__ __align__(16) float As[KS][LPAD];
    __shared__ __align__(16) float Bs[KS][LPAD];
    __shared__ __align__(16) float Cs[TS][LPAD];

    float acc[4][4] = {};
    const int arow = tid >> 2;
    const int akc  = (tid & 3) * 4;
    const int brw  = tid >> 4;
    const int bnc  = (tid & 15) * 4;

    for (int k0 = 0; k0 < DD; k0 += KS) {
        float4 av = *reinterpret_cast<const float4*>(&SO[(m0 + arow) * DD + k0 + akc]);
        As[akc + 0][arow] = av.x;
        As[akc + 1][arow] = av.y;
        As[akc + 2][arow] = av.z;
        As[akc + 3][arow] = av.w;
        float4 bv = *reinterpret_cast<const float4*>(&W[(k0 + brw) * AA + n0 + bnc]);
        *reinterpret_cast<float4*>(&Bs[brw][bnc]) = bv;
        __syncthreads();
        #pragma unroll
        for (int kk = 0; kk < KS; ++kk) {
            float4 a4 = *reinterpret_cast<const float4*>(&As[kk][ty * 4]);
            float4 b4 = *reinterpret_cast<const float4*>(&Bs[kk][tx * 4]);
            float av_[4] = {a4.x, a4.y, a4.z, a4.w};
            float bv_[4] = {b4.x, b4.y, b4.z, b4.w};
            #pragma unroll
            for (int i = 0; i < 4; ++i)
                #pragma unroll
                for (int j = 0; j < 4; ++j)
                    acc[i][j] = fmaf(av_[i], bv_[j], acc[i][j]);
        }
        __syncthreads();
    }

    if (mode == 1) {
        #pragma unroll
        for (int i = 0; i < 4; ++i) {
            int m = m0 + ty * 4 + i;
            float4 v;
            v.x = __builtin_amdgcn_exp2f((acc[i][0] + bias[n0 + tx * 4 + 0]) * PS);
            v.y = __builtin_amdgcn_exp2f((acc[i][1] + bias[n0 + tx * 4 + 1]) * PS);
            v.z = __builtin_amdgcn_exp2f((acc[i][2] + bias[n0 + tx * 4 + 2]) * PS);
            v.w = __builtin_amdgcn_exp2f((acc[i][3] + bias[n0 + tx * 4 + 3]) * PS);
            *reinterpret_cast<float4*>(&Es[(size_t)m * AA + n0 + tx * 4]) = v;
        }
    } else if (mode == 0) {
        #pragma unroll
        for (int i = 0; i < 4; ++i)
            #pragma unroll
            for (int j = 0; j < 4; ++j)
                Cs[tx * 4 + j][ty * 4 + i] =
                    __builtin_amdgcn_exp2f((acc[i][j] + bias[n0 + tx * 4 + j]) * PS);
        __syncthreads();
        int row = tid >> 2, part = tid & 3;
        int bb = m0 >> 8;
        int tstart = (m0 & 255) + part * 16;
        float* dst = &EhT[bb * (AA * TT) + (n0 + row) * TT + tstart];
        #pragma unroll
        for (int q = 0; q < 4; ++q) {
            float4 v = *reinterpret_cast<const float4*>(&Cs[row][part * 16 + q * 4]);
            *reinterpret_cast<float4*>(&dst[q * 4]) = v;
        }
    } else {
        int bb = m0 >> 8;
        #pragma unroll
        for (int i = 0; i < 4; ++i) {
            float p = 0.f;
            #pragma unroll
            for (int j = 0; j < 4; ++j) {
                int n = n0 + tx * 4 + j;
                float x = acc[i][j] + bias[n] + ii[bb * AA + n];
                p = fmaf(iv[n], fast_tanh(x), p);
            }
            Cs[ty * 4 + i][tx] = p;
        }
        __syncthreads();
        if (tid < 64) {
            float s = 0.f;
            #pragma unroll
            for (int k = 0; k < 16; ++k) s += Cs[tid][k];
            ipart[blockIdx.y * 2048 + m0 + tid] = s;
        }
    }
}

// ---------------- k3_fused: 512 slot blocks (2/CU exactly); blocks 0..7 also do intent ---
// Thread = (s-pair sp, a-quarter ah); h-loads software-pipelined 4-deep x2.
__global__ __launch_bounds__(512) void k3_fused(const float* __restrict__ SO,
                                                const float* __restrict__ EhT,
                                                const float* __restrict__ Es,
                                                const float* __restrict__ sv_g,
                                                const float* __restrict__ ipart,
                                                float* __restrict__ out_cslot,
                                                float* __restrict__ out_cint,
                                                int npart) {
    const int bid = blockIdx.x;
    const int tid = threadIdx.x;

    __shared__ __align__(16) float est[512][4];   // [a][q]
    __shared__ __align__(16) float sv[512];
    __shared__ __align__(8)  float yp[4][4][256]; // [ah][q][s]
    __shared__ __align__(16) float wlt[256][4];
    __shared__ float redm[4][2];
    __shared__ float reds[4][2];
    __shared__ float redI[256];
    __shared__ float wlI[256];

    const int b = bid & 7;          // XCD-affine
    const int t0 = (bid >> 3) * 4;
    const int sp = tid & 127;       // s-pair index: s = 2*sp, 2*sp+1
    const int ah = tid >> 7;        // 0..3, a-quarter
    const int abase = ah * 128;

    // stage est (transposed gather) + sv
    {
        const float* esrc = &Es[(size_t)(b * 256 + t0) * 512];
        #pragma unroll
        for (int i = tid; i < 2048; i += 512) est[i & 511][i >> 9] = esrc[i];
        sv[tid] = sv_g[tid];
    }
    __syncthreads();

    // ---- score: 128 a x 4 t x 2 s per thread, h-loads double-pipelined ----
    const float* hp = &EhT[((size_t)b * 512 + abase) * 256 + 2 * sp];
    float a00=0.f,a01=0.f,a10=0.f,a11=0.f,a20=0.f,a21=0.f,a30=0.f,a31=0.f;
    float2 h0[4], h1[4];
    #pragma unroll
    for (int u = 0; u < 4; ++u)
        h0[u] = *reinterpret_cast<const float2*>(&hp[u * 256]);

    #define SCORE4(A0, H) do {                                                         \
        float4 v4 = *reinterpret_cast<const float4*>(&sv[abase + (A0)]);               \
        _Pragma("unroll")                                                              \
        for (int u = 0; u < 4; ++u) {                                                  \
            float4 e4 = *reinterpret_cast<const float4*>(&est[abase + (A0) + u][0]);   \
            float vv = (u == 0) ? v4.x : (u == 1) ? v4.y : (u == 2) ? v4.z : v4.w;     \
            float hx = H[u].x, hy = H[u].y;                                            \
            a00 = fmaf(vv, __builtin_amdgcn_rcpf(fmaf(hx, e4.x, 1.f)), a00);           \
            a01 = fmaf(vv, __builtin_amdgcn_rcpf(fmaf(hy, e4.x, 1.f)), a01);           \
            a10 = fmaf(vv, __builtin_amdgcn_rcpf(fmaf(hx, e4.y, 1.f)), a10);           \
            a11 = fmaf(vv, __builtin_amdgcn_rcpf(fmaf(hy, e4.y, 1.f)), a11);           \
            a20 = fmaf(vv, __builtin_amdgcn_rcpf(fmaf(hx, e4.z, 1.f)), a20);           \
            a21 = fmaf(vv, __builtin_amdgcn_rcpf(fmaf(hy, e4.z, 1.f)), a21);           \
            a30 = fmaf(vv, __builtin_amdgcn_rcpf(fmaf(hx, e4.w, 1.f)), a30);           \
            a31 = fmaf(vv, __builtin_amdgcn_rcpf(fmaf(hy, e4.w, 1.f)), a31);           \
        }                                                                              \
    } while (0)

    for (int a0 = 0; a0 < 128; a0 += 8) {
        #pragma unroll
        for (int u = 0; u < 4; ++u)
            h1[u] = *reinterpret_cast<const float2*>(&hp[(a0 + 4 + u) * 256]);
        SCORE4(a0, h0);
        #pragma unroll
        for (int u = 0; u < 4; ++u)   // over-read at a0=120 stays inside ws (Es region)
            h0[u] = *reinterpret_cast<const float2*>(&hp[(a0 + 8 + u) * 256]);
        SCORE4(a0 + 4, h1);
    }

    *reinterpret_cast<float2*>(&yp[ah][0][2 * sp]) = make_float2(a00, a01);
    *reinterpret_cast<float2*>(&yp[ah][1][2 * sp]) = make_float2(a10, a11);
    *reinterpret_cast<float2*>(&yp[ah][2][2 * sp]) = make_float2(a20, a21);
    *reinterpret_cast<float2*>(&yp[ah][3][2 * sp]) = make_float2(a30, a31);
    __syncthreads();

    // ---- softmax: group g = ah owns t-row g; 128 threads handle s=L and s=L+128 ----
    {
        const int g = ah;
        const int L = sp;
        const int w2 = (tid >> 6) & 1;
        float yL = (yp[0][g][L]       + yp[1][g][L])       + (yp[2][g][L]       + yp[3][g][L]);
        float yH = (yp[0][g][L + 128] + yp[1][g][L + 128]) + (yp[2][g][L + 128] + yp[3][g][L + 128]);
        float mn = fminf(yL, yH);
        #pragma unroll
        for (int off = 1; off < 64; off <<= 1)
            mn = fminf(mn, __shfl_xor(mn, off));
        if ((tid & 63) == 0) redm[g][w2] = mn;
        __syncthreads();
        mn = fminf(redm[g][0], redm[g][1]);
        float eL = __builtin_amdgcn_exp2f(PS * (mn - yL));
        float eH = __builtin_amdgcn_exp2f(PS * (mn - yH));
        float sm = eL + eH;
        #pragma unroll
        for (int off = 1; off < 64; off <<= 1)
            sm += __shfl_xor(sm, off);
        if ((tid & 63) == 0) reds[g][w2] = sm;
        __syncthreads();
        sm = reds[g][0] + reds[g][1];
        float rs = __builtin_amdgcn_rcpf(sm);
        wlt[L][g]       = eL * rs;
        wlt[L + 128][g] = eH * rs;
    }
    __syncthreads();

    // ---- PV: thread owns d = tid, 4 t-rows ----
    {
        const int d = tid;
        const float* sop = &SO[(size_t)b * 256 * 512 + d];
        float c0 = 0.f, c1 = 0.f, c2 = 0.f, c3 = 0.f;
        for (int s0 = 0; s0 < 256; s0 += 4) {
            float so[4];
            #pragma unroll
            for (int u = 0; u < 4; ++u) so[u] = sop[(s0 + u) * 512];
            #pragma unroll
            for (int u = 0; u < 4; ++u) {
                float4 w4 = *reinterpret_cast<const float4*>(&wlt[s0 + u][0]);
                c0 = fmaf(w4.x, so[u], c0);
                c1 = fmaf(w4.y, so[u], c1);
                c2 = fmaf(w4.z, so[u], c2);
                c3 = fmaf(w4.w, so[u], c3);
            }
        }
        float* op = &out_cslot[((size_t)(b * 256 + t0)) * 512 + d];
        op[0] = c0; op[512] = c1; op[1024] = c2; op[1536] = c3;
    }

    // ---- intent: folded into blocks 0..7 (b == bid here) ----
    if (bid < 8) {
        __syncthreads();
        float sc = 0.f;
        if (tid < 256) {
            for (int nb = 0; nb < npart; ++nb) sc += ipart[nb * 2048 + b * 256 + tid];
            redI[tid] = sc;
        }
        __syncthreads();
        for (int off = 128; off > 0; off >>= 1) {
            if (tid < off) redI[tid] = fmaxf(redI[tid], redI[tid + off]);
            __syncthreads();
        }
        float mx = redI[0];
        __syncthreads();
        float e = 0.f;
        if (tid < 256) { e = __builtin_amdgcn_exp2f((sc - mx) * LOG2E); redI[tid] = e; }
        __syncthreads();
        for (int off = 128; off > 0; off >>= 1) {
            if (tid < off) redI[tid] += redI[tid + off];
            __syncthreads();
        }
        if (tid < 256) wlI[tid] = e * __builtin_amdgcn_rcpf(redI[0]);
        __syncthreads();
        const int d = tid;
        float c = 0.f;
        const float* sop = &SO[(size_t)b * 256 * 512 + d];
        for (int s0 = 0; s0 < 256; s0 += 4) {
            float so[4];
            #pragma unroll
            for (int u = 0; u < 4; ++u) so[u] = sop[(s0 + u) * 512];
            #pragma unroll
            for (int u = 0; u < 4; ++u) c = fmaf(wlI[s0 + u], so[u], c);
        }
        out_cint[(size_t)b * 512 + d] = c;
    }
}

extern "C" void kernel_launch(void* const* d_in, const int* in_sizes, int n_in,
                              void* d_out, int out_size, void* d_ws, size_t ws_size,
                              hipStream_t stream) {
    const float* SO  = (const float*)d_in[0];
    const float* FS  = (const float*)d_in[1];
    const float* IV  = (const float*)d_in[2];
    const float* Wih = (const float*)d_in[3];
    const float* bih = (const float*)d_in[4];
    const float* Wii = (const float*)d_in[5];
    const float* bii = (const float*)d_in[6];
    const float* SV  = (const float*)d_in[7];
    const float* Wsh = (const float*)d_in[8];
    const float* bsh = (const float*)d_in[9];
    const float* Wsi = (const float*)d_in[10];
    const float* bsi = (const float*)d_in[11];

    float* ws    = (float*)d_ws;
    float* EhT   = ws;                 // [8][512][256]  exp2'd   1,048,576 f
    float* Es    = ws + 1048576;       // [2048][512]    exp2'd   1,048,576 f
    float* ii    = ws + 2097152;       // [8][512]                4,096 f
    float* ipart = ws + 2101248;       // [16][2048]              32,768 f
    ushort* Ast  = (ushort*)(ws + 2134016);  // [2048][1024] bf16
    ushort* Wt   = (ushort*)(ws + 3182592);  // [1536][1024] bf16
    const size_t NEED = (size_t)3969024 * 4;

    float* out_cslot = (float*)d_out;
    float* out_cint  = out_cslot + BB * TT * DD;

    if (ws_size >= NEED) {
        prep<<<1808, 256, 0, stream>>>(SO, Ast, Wsh, Wsi, Wih, Wt, FS, Wii, bii, ii);
        gemm_mfma<<<dim3(32, 24), 256, 0, stream>>>(Ast, Wt, bsh, bsi, bih, ii, IV,
                                                    EhT, Es, ipart);
        k3_fused<<<512, 512, 0, stream>>>(SO, EhT, Es, SV, ipart, out_cslot, out_cint, 16);
    } else {
        k0_ii<<<dim3(BB, 2), 256, 0, stream>>>(FS, Wii, bii, ii);
        k1_gemm_old<<<dim3(32, 8, 3), 256, 0, stream>>>(SO, Wsh, bsh, Wsi, bsi, Wih, bih,
                                                        ii, IV, EhT, Es, ipart);
        k3_fused<<<512, 512, 0, stream>>>(SO, EhT, Es, SV, ipart, out_cslot, out_cint, 8);
    }
}